// Round 2
// baseline (4018.537 us; speedup 1.0000x reference)
//
#include <hip/hip_runtime.h>
#include <hip/hip_bf16.h>
#include <cstdint>

#define NN   50000      // nodes
#define NE   800000     // edges (without self loops)
#define NET  850000     // edges + self loops
#define FIN  128
#define FH1  256        // heads*C layer1
#define HD   64
#define NG   64
#define OUTC 10

__device__ __forceinline__ float bf2f(unsigned short u) {
    union { unsigned int i; float f; } v; v.i = ((unsigned int)u) << 16; return v.f;
}
__device__ __forceinline__ unsigned short f2bf(float f) {
    union { float fl; unsigned int i; } v; v.fl = f;
    unsigned int x = v.i;
    return (unsigned short)((x + 0x7FFFu + ((x >> 16) & 1u)) >> 16);
}
__device__ __forceinline__ float leakyr(float v) { return v > 0.f ? v : 0.2f * v; }
__device__ __forceinline__ float elu1(float v)  { return v > 0.f ? v : expm1f(v); }

// ---------------- K1: xp1 = x @ W1 (bf16 out) + scores s1,d1 ----------------
__global__ __launch_bounds__(256) void k_gemm1(
    const float* __restrict__ x, const float* __restrict__ W1,
    const float* __restrict__ asrc, const float* __restrict__ adst,
    unsigned short* __restrict__ xp1, float* __restrict__ s1, float* __restrict__ d1)
{
    __shared__ float xs[16][FIN];
    int row0 = blockIdx.x * 16;
    int tid = threadIdx.x;
    {
        int r = tid >> 4;              // 0..15
        int k = (tid & 15) * 8;        // 0..120
        int gr = row0 + r;
        if (gr < NN) {
            const float4* p = reinterpret_cast<const float4*>(x + (size_t)gr * FIN + k);
            *reinterpret_cast<float4*>(&xs[r][k])     = p[0];
            *reinterpret_cast<float4*>(&xs[r][k + 4]) = p[1];
        } else {
            #pragma unroll
            for (int j = 0; j < 8; j++) xs[r][k + j] = 0.f;
        }
    }
    __syncthreads();
    int c = tid;                        // 0..255 output column
    float acc[16];
    #pragma unroll
    for (int r = 0; r < 16; r++) acc[r] = 0.f;
    for (int k = 0; k < FIN; k += 4) {
        float w0 = W1[(size_t)(k + 0) * FH1 + c];
        float w1 = W1[(size_t)(k + 1) * FH1 + c];
        float w2 = W1[(size_t)(k + 2) * FH1 + c];
        float w3 = W1[(size_t)(k + 3) * FH1 + c];
        #pragma unroll
        for (int r = 0; r < 16; r++) {
            float4 xv = *reinterpret_cast<const float4*>(&xs[r][k]);
            acc[r] = fmaf(xv.x, w0, acc[r]);
            acc[r] = fmaf(xv.y, w1, acc[r]);
            acc[r] = fmaf(xv.z, w2, acc[r]);
            acc[r] = fmaf(xv.w, w3, acc[r]);
        }
    }
    float as = asrc[c], ad = adst[c];
    int head = c >> 6;                  // wave id == head
    int lane = tid & 63;
    #pragma unroll
    for (int r = 0; r < 16; r++) {
        int gr = row0 + r;
        if (gr < NN) xp1[(size_t)gr * FH1 + c] = f2bf(acc[r]);
        float sv = acc[r] * as, dv = acc[r] * ad;
        #pragma unroll
        for (int off = 32; off >= 1; off >>= 1) {
            sv += __shfl_xor(sv, off);
            dv += __shfl_xor(dv, off);
        }
        if (lane == 0 && gr < NN) { s1[gr * 4 + head] = sv; d1[gr * 4 + head] = dv; }
    }
}

// ---------------- K2: layer-1 softmax denominators ----------------
__global__ __launch_bounds__(256) void k_den1(
    const int* __restrict__ ei, const float* __restrict__ s1,
    const float* __restrict__ d1, float* __restrict__ den1)
{
    int e = blockIdx.x * 256 + threadIdx.x;
    if (e >= NET) return;
    int src, dst;
    if (e < NE) { src = ei[e]; dst = ei[NE + e]; }
    else        { src = dst = e - NE; }
    float4 s = *reinterpret_cast<const float4*>(s1 + (size_t)src * 4);
    float4 d = *reinterpret_cast<const float4*>(d1 + (size_t)dst * 4);
    float e0 = expf(leakyr(s.x + d.x));
    float e1 = expf(leakyr(s.y + d.y));
    float e2 = expf(leakyr(s.z + d.z));
    float e3 = expf(leakyr(s.w + d.w));
    float* p = den1 + (size_t)dst * 4;
    atomicAdd(p + 0, e0); atomicAdd(p + 1, e1);
    atomicAdd(p + 2, e2); atomicAdd(p + 3, e3);
}

// ---------------- K3: layer-1 messages (one wave per edge) ----------------
__global__ __launch_bounds__(256) void k_msg1(
    const int* __restrict__ ei, const float* __restrict__ s1,
    const float* __restrict__ d1, const unsigned short* __restrict__ xp1,
    float* __restrict__ out1)
{
    int w = threadIdx.x >> 6;
    int lane = threadIdx.x & 63;
    int e = blockIdx.x * 4 + w;
    if (e >= NET) return;
    int src, dst;
    if (e < NE) { src = ei[e]; dst = ei[NE + e]; }
    else        { src = dst = e - NE; }
    int head = lane >> 4;                        // 4 cols per lane -> head = lane/16
    float s = s1[(size_t)src * 4 + head];
    float d = d1[(size_t)dst * 4 + head];
    float ex = expf(leakyr(s + d));              // un-normalized alpha (divide later)
    int c0 = lane * 4;
    ushort4 xv = *reinterpret_cast<const ushort4*>(xp1 + (size_t)src * FH1 + c0);
    float* op = out1 + (size_t)dst * FH1 + c0;
    atomicAdd(op + 0, bf2f(xv.x) * ex);
    atomicAdd(op + 1, bf2f(xv.y) * ex);
    atomicAdd(op + 2, bf2f(xv.z) * ex);
    atomicAdd(op + 3, bf2f(xv.w) * ex);
}

// ---------------- K4: h1 = elu(out1/den1 + b1) -> bf16 ----------------
__global__ __launch_bounds__(256) void k_h1(
    const float* __restrict__ out1, const float* __restrict__ den1,
    const float* __restrict__ b1, unsigned short* __restrict__ h1)
{
    int i4 = blockIdx.x * 256 + threadIdx.x;
    const int total = NN * FH1 / 4;
    if (i4 >= total) return;
    int idx = i4 * 4;
    int n = idx >> 8;
    int c = idx & 255;
    int head = c >> 6;
    float inv = 1.0f / den1[n * 4 + head];
    float4 o = *reinterpret_cast<const float4*>(out1 + idx);
    float4 b = *reinterpret_cast<const float4*>(b1 + c);
    ushort4 st;
    st.x = f2bf(elu1(fmaf(o.x, inv, b.x)));
    st.y = f2bf(elu1(fmaf(o.y, inv, b.y)));
    st.z = f2bf(elu1(fmaf(o.z, inv, b.z)));
    st.w = f2bf(elu1(fmaf(o.w, inv, b.w)));
    *reinterpret_cast<ushort4*>(h1 + idx) = st;
}

// ---------------- K5: xp2 = h1 @ W2 + scores s2,d2 ----------------
__global__ __launch_bounds__(256) void k_gemm2(
    const unsigned short* __restrict__ h1, const float* __restrict__ W2,
    const float* __restrict__ asrc2, const float* __restrict__ adst2,
    float* __restrict__ xp2, float* __restrict__ s2, float* __restrict__ d2)
{
    __shared__ unsigned short hs[16][FH1];
    int row0 = blockIdx.x * 16;
    int tid = threadIdx.x;
    {
        int lr = tid >> 4;             // 0..15
        int k = (tid & 15) * 16;       // 16 ushorts each (two uint4 loads!)
        int gr = row0 + lr;
        uint4 v0 = make_uint4(0, 0, 0, 0);
        uint4 v1 = make_uint4(0, 0, 0, 0);
        if (gr < NN) {
            const uint4* p = reinterpret_cast<const uint4*>(h1 + (size_t)gr * FH1 + k);
            v0 = p[0];
            v1 = p[1];
        }
        *reinterpret_cast<uint4*>(&hs[lr][k])     = v0;
        *reinterpret_cast<uint4*>(&hs[lr][k + 8]) = v1;
    }
    __syncthreads();
    int c = tid & 63;
    int rg = tid >> 6;                  // 4 row groups
    float acc[4] = {0.f, 0.f, 0.f, 0.f};
    for (int k = 0; k < FH1; k += 8) {
        float w[8];
        #pragma unroll
        for (int j = 0; j < 8; j++) w[j] = W2[(size_t)(k + j) * HD + c];
        #pragma unroll
        for (int rr = 0; rr < 4; rr++) {
            int lr = rg * 4 + rr;
            unsigned short xs8[8];
            *reinterpret_cast<uint4*>(xs8) = *reinterpret_cast<const uint4*>(&hs[lr][k]);
            float a = acc[rr];
            #pragma unroll
            for (int j = 0; j < 8; j++) a = fmaf(bf2f(xs8[j]), w[j], a);
            acc[rr] = a;
        }
    }
    float as = asrc2[c], ad = adst2[c];
    int lane = tid & 63;
    #pragma unroll
    for (int rr = 0; rr < 4; rr++) {
        int gr = row0 + rg * 4 + rr;
        if (gr < NN) xp2[(size_t)gr * HD + c] = acc[rr];
        float sv = acc[rr] * as, dv = acc[rr] * ad;
        #pragma unroll
        for (int off = 32; off >= 1; off >>= 1) {
            sv += __shfl_xor(sv, off);
            dv += __shfl_xor(dv, off);
        }
        if (lane == 0 && gr < NN) { s2[gr] = sv; d2[gr] = dv; }
    }
}

// ---------------- K6: layer-2 softmax denominators ----------------
__global__ __launch_bounds__(256) void k_den2(
    const int* __restrict__ ei, const float* __restrict__ s2,
    const float* __restrict__ d2, float* __restrict__ den2)
{
    int e = blockIdx.x * 256 + threadIdx.x;
    if (e >= NET) return;
    int src, dst;
    if (e < NE) { src = ei[e]; dst = ei[NE + e]; }
    else        { src = dst = e - NE; }
    float ex = expf(leakyr(s2[src] + d2[dst]));
    atomicAdd(&den2[dst], ex);
}

// ---------------- K7: layer-2 messages (16 lanes per edge) ----------------
__global__ __launch_bounds__(256) void k_msg2(
    const int* __restrict__ ei, const float* __restrict__ s2,
    const float* __restrict__ d2, const float* __restrict__ xp2,
    float* __restrict__ out2)
{
    int t = threadIdx.x;
    int el = t >> 4;                   // 16 edges per block
    int l = t & 15;
    int e = blockIdx.x * 16 + el;
    if (e >= NET) return;
    int src, dst;
    if (e < NE) { src = ei[e]; dst = ei[NE + e]; }
    else        { src = dst = e - NE; }
    float ex = expf(leakyr(s2[src] + d2[dst]));
    int c0 = l * 4;
    float4 xv = *reinterpret_cast<const float4*>(xp2 + (size_t)src * HD + c0);
    float* op = out2 + (size_t)dst * HD + c0;
    atomicAdd(op + 0, xv.x * ex);
    atomicAdd(op + 1, xv.y * ex);
    atomicAdd(op + 2, xv.z * ex);
    atomicAdd(op + 3, xv.w * ex);
}

// ---------------- K8: per-graph mean pool of elu(out2/den2 + b2) ----------------
__global__ __launch_bounds__(256) void k_pool(
    const float* __restrict__ out2, const float* __restrict__ den2,
    const float* __restrict__ b2, const int* __restrict__ batch,
    float* __restrict__ pooled)
{
    int g = blockIdx.x;
    int lo = 0, hi = NN;
    while (lo < hi) { int m = (lo + hi) >> 1; if (batch[m] < g) lo = m + 1; else hi = m; }
    int start = lo;
    hi = NN;
    while (lo < hi) { int m = (lo + hi) >> 1; if (batch[m] < g + 1) lo = m + 1; else hi = m; }
    int end = lo;
    int c = threadIdx.x & 63;
    int rg = threadIdx.x >> 6;
    float b = b2[c];
    float sum = 0.f;
    for (int n = start + rg; n < end; n += 4) {
        float v = out2[(size_t)n * HD + c] / den2[n] + b;
        sum += elu1(v);
    }
    __shared__ float red[4][64];
    red[rg][c] = sum;
    __syncthreads();
    if (threadIdx.x < 64) {
        float tot = red[0][c] + red[1][c] + red[2][c] + red[3][c];
        float cnt = (float)(end - start);
        pooled[g * HD + c] = tot / fmaxf(cnt, 1.f);
    }
}

// ---------------- K9: final linear [64,64]@[64,10]+bl ----------------
__global__ __launch_bounds__(256) void k_final(
    const float* __restrict__ pooled, const float* __restrict__ Wl,
    const float* __restrict__ bl, float* __restrict__ out)
{
    int t = blockIdx.x * 256 + threadIdx.x;
    if (t >= NG * OUTC) return;
    int g = t / OUTC, o = t % OUTC;
    float acc = bl[o];
    #pragma unroll
    for (int k = 0; k < HD; k++)
        acc = fmaf(pooled[g * HD + k], Wl[k * OUTC + o], acc);
    out[t] = acc;
}

extern "C" void kernel_launch(void* const* d_in, const int* in_sizes, int n_in,
                              void* d_out, int out_size, void* d_ws, size_t ws_size,
                              hipStream_t stream) {
    const float* x     = (const float*)d_in[0];
    const int*   ei    = (const int*)d_in[1];
    const int*   batch = (const int*)d_in[2];
    const float* W1    = (const float*)d_in[3];
    const float* as1   = (const float*)d_in[4];
    const float* ad1   = (const float*)d_in[5];
    const float* b1    = (const float*)d_in[6];
    const float* W2    = (const float*)d_in[7];
    const float* as2   = (const float*)d_in[8];
    const float* ad2   = (const float*)d_in[9];
    const float* b2    = (const float*)d_in[10];
    const float* Wl    = (const float*)d_in[11];
    const float* bl    = (const float*)d_in[12];
    float* out = (float*)d_out;

    char* w = (char*)d_ws;
    size_t off = 0;
    auto alloc = [&](size_t bytes) {
        void* p = (void*)(w + off);
        off = (off + bytes + 255) & ~(size_t)255;
        return p;
    };
    // zero-initialized block (accumulators) -- keep contiguous at the front
    float* den1   = (float*)alloc((size_t)NN * 4 * 4);
    float* out1   = (float*)alloc((size_t)NN * FH1 * 4);
    float* den2   = (float*)alloc((size_t)NN * 4);
    float* out2   = (float*)alloc((size_t)NN * HD * 4);
    float* pooled = (float*)alloc((size_t)NG * HD * 4);
    size_t zbytes = off;
    unsigned short* xp1 = (unsigned short*)alloc((size_t)NN * FH1 * 2); // later aliased as h1
    float* s1  = (float*)alloc((size_t)NN * 4 * 4);
    float* d1s = (float*)alloc((size_t)NN * 4 * 4);
    float* xp2 = (float*)alloc((size_t)NN * HD * 4);
    float* s2  = (float*)alloc((size_t)NN * 4);
    float* d2s = (float*)alloc((size_t)NN * 4);
    unsigned short* h1 = xp1;   // alias: xp1 dead after k_msg1

    hipMemsetAsync(d_ws, 0, zbytes, stream);

    k_gemm1<<<(NN + 15) / 16, 256, 0, stream>>>(x, W1, as1, ad1, xp1, s1, d1s);
    k_den1 <<<(NET + 255) / 256, 256, 0, stream>>>(ei, s1, d1s, den1);
    k_msg1 <<<(NET + 3) / 4, 256, 0, stream>>>(ei, s1, d1s, xp1, out1);
    k_h1   <<<(NN * FH1 / 4 + 255) / 256, 256, 0, stream>>>(out1, den1, b1, h1);
    k_gemm2<<<(NN + 15) / 16, 256, 0, stream>>>(h1, W2, as2, ad2, xp2, s2, d2s);
    k_den2 <<<(NET + 255) / 256, 256, 0, stream>>>(ei, s2, d2s, den2);
    k_msg2 <<<(NET + 15) / 16, 256, 0, stream>>>(ei, s2, d2s, xp2, out2);
    k_pool <<<NG, 256, 0, stream>>>(out2, den2, b2, batch, pooled);
    k_final<<<(NG * OUTC + 255) / 256, 256, 0, stream>>>(pooled, Wl, bl, out);
}

// Round 3
// 569.426 us; speedup vs baseline: 7.0572x; 7.0572x over previous
//
#include <hip/hip_runtime.h>
#include <hip/hip_bf16.h>
#include <cstdint>

#define NN   50000      // nodes
#define NE   800000     // edges (without self loops)
#define NET  850000     // edges + self loops
#define FIN  128
#define FH1  256        // heads*C layer1
#define HD   64
#define NG   64
#define OUTC 10

__device__ __forceinline__ float bf2f(unsigned short u) {
    union { unsigned int i; float f; } v; v.i = ((unsigned int)u) << 16; return v.f;
}
__device__ __forceinline__ unsigned short f2bf(float f) {
    union { float fl; unsigned int i; } v; v.fl = f;
    unsigned int x = v.i;
    return (unsigned short)((x + 0x7FFFu + ((x >> 16) & 1u)) >> 16);
}
__device__ __forceinline__ float leakyr(float v) { return v > 0.f ? v : 0.2f * v; }
__device__ __forceinline__ float elu1(float v)  { return v > 0.f ? v : expm1f(v); }

// ---------------- K1: xp1 = x @ W1 (bf16 out) + scores s1,d1 ----------------
__global__ __launch_bounds__(256) void k_gemm1(
    const float* __restrict__ x, const float* __restrict__ W1,
    const float* __restrict__ asrc, const float* __restrict__ adst,
    unsigned short* __restrict__ xp1, float* __restrict__ s1, float* __restrict__ d1)
{
    __shared__ float xs[16][FIN];
    int row0 = blockIdx.x * 16;
    int tid = threadIdx.x;
    {
        int r = tid >> 4;              // 0..15
        int k = (tid & 15) * 8;        // 0..120
        int gr = row0 + r;
        if (gr < NN) {
            const float4* p = reinterpret_cast<const float4*>(x + (size_t)gr * FIN + k);
            *reinterpret_cast<float4*>(&xs[r][k])     = p[0];
            *reinterpret_cast<float4*>(&xs[r][k + 4]) = p[1];
        } else {
            #pragma unroll
            for (int j = 0; j < 8; j++) xs[r][k + j] = 0.f;
        }
    }
    __syncthreads();
    int c = tid;                        // 0..255 output column
    float acc[16];
    #pragma unroll
    for (int r = 0; r < 16; r++) acc[r] = 0.f;
    for (int k = 0; k < FIN; k += 4) {
        float w0 = W1[(size_t)(k + 0) * FH1 + c];
        float w1 = W1[(size_t)(k + 1) * FH1 + c];
        float w2 = W1[(size_t)(k + 2) * FH1 + c];
        float w3 = W1[(size_t)(k + 3) * FH1 + c];
        #pragma unroll
        for (int r = 0; r < 16; r++) {
            float4 xv = *reinterpret_cast<const float4*>(&xs[r][k]);
            acc[r] = fmaf(xv.x, w0, acc[r]);
            acc[r] = fmaf(xv.y, w1, acc[r]);
            acc[r] = fmaf(xv.z, w2, acc[r]);
            acc[r] = fmaf(xv.w, w3, acc[r]);
        }
    }
    float as = asrc[c], ad = adst[c];
    int head = c >> 6;                  // wave id == head
    int lane = tid & 63;
    #pragma unroll
    for (int r = 0; r < 16; r++) {
        int gr = row0 + r;
        if (gr < NN) xp1[(size_t)gr * FH1 + c] = f2bf(acc[r]);
        float sv = acc[r] * as, dv = acc[r] * ad;
        #pragma unroll
        for (int off = 32; off >= 1; off >>= 1) {
            sv += __shfl_xor(sv, off);
            dv += __shfl_xor(dv, off);
        }
        if (lane == 0 && gr < NN) { s1[gr * 4 + head] = sv; d1[gr * 4 + head] = dv; }
    }
}

// ---------------- CSR build: histogram of dst ----------------
__global__ __launch_bounds__(256) void k_hist(
    const int* __restrict__ ei, int* __restrict__ deg)
{
    int e = blockIdx.x * 256 + threadIdx.x;
    if (e >= NET) return;
    int dst = (e < NE) ? ei[NE + e] : (e - NE);
    atomicAdd(&deg[dst], 1);
}

// ---------------- CSR build: exclusive scan deg -> rowptr (single block) ----------------
__global__ __launch_bounds__(256) void k_scan(
    const int* __restrict__ deg, int* __restrict__ rowptr)
{
    __shared__ int part[256];
    const int CH = (NN + 255) / 256;   // 196 elements per thread
    int t = threadIdx.x;
    int base = t * CH;
    int s = 0;
    for (int i = 0; i < CH; i++) {
        int idx = base + i;
        if (idx < NN) s += deg[idx];
    }
    part[t] = s;
    __syncthreads();
    // Hillis-Steele inclusive scan of part[]
    for (int off = 1; off < 256; off <<= 1) {
        int v = (t >= off) ? part[t - off] : 0;
        __syncthreads();
        part[t] += v;
        __syncthreads();
    }
    int run = part[t] - s;             // exclusive prefix of this thread's chunk
    for (int i = 0; i < CH; i++) {
        int idx = base + i;
        if (idx < NN) { rowptr[idx] = run; run += deg[idx]; }
    }
    if (t == 0) rowptr[NN] = NET;
}

// ---------------- CSR build: scatter edge srcs into slots ----------------
__global__ __launch_bounds__(256) void k_scatter(
    const int* __restrict__ ei, const int* __restrict__ rowptr,
    int* __restrict__ cursor, int* __restrict__ eidx)
{
    int e = blockIdx.x * 256 + threadIdx.x;
    if (e >= NET) return;
    int src, dst;
    if (e < NE) { src = ei[e]; dst = ei[NE + e]; }
    else        { src = dst = e - NE; }
    int pos = atomicAdd(&cursor[dst], 1);
    eidx[rowptr[dst] + pos] = src;
}

// ---------------- K3': layer-1 pull (one wave per dst node) ----------------
// Fuses den1 + msg1 + h1: h1[n] = elu( (sum_e ex*xp1[src]) / (sum_e ex) + b1 )
__global__ __launch_bounds__(256) void k_pull1(
    const int* __restrict__ rowptr, const int* __restrict__ eidx,
    const float* __restrict__ s1, const float* __restrict__ d1,
    const unsigned short* __restrict__ xp1, const float* __restrict__ b1,
    unsigned short* __restrict__ h1)
{
    int wv = threadIdx.x >> 6;
    int lane = threadIdx.x & 63;
    int n = blockIdx.x * 4 + wv;
    if (n >= NN) return;
    int head = lane >> 4;                  // 16 lanes per head
    int c0 = lane * 4;                     // 4 consecutive cols per lane
    float dv = d1[(size_t)n * 4 + head];
    int jb = rowptr[n], je = rowptr[n + 1];
    float a0 = 0.f, a1 = 0.f, a2 = 0.f, a3 = 0.f;
    float den = 0.f;
    for (int j = jb; j < je; j++) {
        int src = eidx[j];
        float ex = expf(leakyr(s1[(size_t)src * 4 + head] + dv));
        ushort4 xv = *reinterpret_cast<const ushort4*>(xp1 + (size_t)src * FH1 + c0);
        a0 = fmaf(bf2f(xv.x), ex, a0);
        a1 = fmaf(bf2f(xv.y), ex, a1);
        a2 = fmaf(bf2f(xv.z), ex, a2);
        a3 = fmaf(bf2f(xv.w), ex, a3);
        den += ex;                         // same ex across the 16-lane head group
    }
    float inv = 1.0f / den;
    float4 b = *reinterpret_cast<const float4*>(b1 + c0);
    ushort4 st;
    st.x = f2bf(elu1(fmaf(a0, inv, b.x)));
    st.y = f2bf(elu1(fmaf(a1, inv, b.y)));
    st.z = f2bf(elu1(fmaf(a2, inv, b.z)));
    st.w = f2bf(elu1(fmaf(a3, inv, b.w)));
    *reinterpret_cast<ushort4*>(h1 + (size_t)n * FH1 + c0) = st;
}

// ---------------- K5: xp2 = h1 @ W2 + scores s2,d2 ----------------
__global__ __launch_bounds__(256) void k_gemm2(
    const unsigned short* __restrict__ h1, const float* __restrict__ W2,
    const float* __restrict__ asrc2, const float* __restrict__ adst2,
    float* __restrict__ xp2, float* __restrict__ s2, float* __restrict__ d2)
{
    __shared__ unsigned short hs[16][FH1];
    int row0 = blockIdx.x * 16;
    int tid = threadIdx.x;
    {
        int lr = tid >> 4;             // 0..15
        int k = (tid & 15) * 16;       // 16 ushorts each (two uint4 loads)
        int gr = row0 + lr;
        uint4 v0 = make_uint4(0, 0, 0, 0);
        uint4 v1 = make_uint4(0, 0, 0, 0);
        if (gr < NN) {
            const uint4* p = reinterpret_cast<const uint4*>(h1 + (size_t)gr * FH1 + k);
            v0 = p[0];
            v1 = p[1];
        }
        *reinterpret_cast<uint4*>(&hs[lr][k])     = v0;
        *reinterpret_cast<uint4*>(&hs[lr][k + 8]) = v1;
    }
    __syncthreads();
    int c = tid & 63;
    int rg = tid >> 6;                  // 4 row groups
    float acc[4] = {0.f, 0.f, 0.f, 0.f};
    for (int k = 0; k < FH1; k += 8) {
        float w[8];
        #pragma unroll
        for (int j = 0; j < 8; j++) w[j] = W2[(size_t)(k + j) * HD + c];
        #pragma unroll
        for (int rr = 0; rr < 4; rr++) {
            int lr = rg * 4 + rr;
            unsigned short xs8[8];
            *reinterpret_cast<uint4*>(xs8) = *reinterpret_cast<const uint4*>(&hs[lr][k]);
            float a = acc[rr];
            #pragma unroll
            for (int j = 0; j < 8; j++) a = fmaf(bf2f(xs8[j]), w[j], a);
            acc[rr] = a;
        }
    }
    float as = asrc2[c], ad = adst2[c];
    int lane = tid & 63;
    #pragma unroll
    for (int rr = 0; rr < 4; rr++) {
        int gr = row0 + rg * 4 + rr;
        if (gr < NN) xp2[(size_t)gr * HD + c] = acc[rr];
        float sv = acc[rr] * as, dv = acc[rr] * ad;
        #pragma unroll
        for (int off = 32; off >= 1; off >>= 1) {
            sv += __shfl_xor(sv, off);
            dv += __shfl_xor(dv, off);
        }
        if (lane == 0 && gr < NN) { s2[gr] = sv; d2[gr] = dv; }
    }
}

// ---------------- K7': layer-2 pull (one wave per dst node) ----------------
// h2[n] = elu( (sum_e ex*xp2[src]) / (sum_e ex) + b2 )
__global__ __launch_bounds__(256) void k_pull2(
    const int* __restrict__ rowptr, const int* __restrict__ eidx,
    const float* __restrict__ s2, const float* __restrict__ d2,
    const float* __restrict__ xp2, const float* __restrict__ b2,
    float* __restrict__ h2)
{
    int wv = threadIdx.x >> 6;
    int lane = threadIdx.x & 63;
    int n = blockIdx.x * 4 + wv;
    if (n >= NN) return;
    float dv = d2[n];
    int jb = rowptr[n], je = rowptr[n + 1];
    float acc = 0.f, den = 0.f;
    for (int j = jb; j < je; j++) {
        int src = eidx[j];
        float ex = expf(leakyr(s2[src] + dv));
        acc = fmaf(xp2[(size_t)src * HD + lane], ex, acc);
        den += ex;
    }
    h2[(size_t)n * HD + lane] = elu1(acc / den + b2[lane]);
}

// ---------------- K8: per-graph mean pool of h2 ----------------
__global__ __launch_bounds__(256) void k_pool(
    const float* __restrict__ h2, const int* __restrict__ batch,
    float* __restrict__ pooled)
{
    int g = blockIdx.x;
    int lo = 0, hi = NN;
    while (lo < hi) { int m = (lo + hi) >> 1; if (batch[m] < g) lo = m + 1; else hi = m; }
    int start = lo;
    hi = NN;
    while (lo < hi) { int m = (lo + hi) >> 1; if (batch[m] < g + 1) lo = m + 1; else hi = m; }
    int end = lo;
    int c = threadIdx.x & 63;
    int rg = threadIdx.x >> 6;
    float sum = 0.f;
    for (int n = start + rg; n < end; n += 4)
        sum += h2[(size_t)n * HD + c];
    __shared__ float red[4][64];
    red[rg][c] = sum;
    __syncthreads();
    if (threadIdx.x < 64) {
        float tot = red[0][c] + red[1][c] + red[2][c] + red[3][c];
        float cnt = (float)(end - start);
        pooled[g * HD + c] = tot / fmaxf(cnt, 1.f);
    }
}

// ---------------- K9: final linear [64,64]@[64,10]+bl ----------------
__global__ __launch_bounds__(256) void k_final(
    const float* __restrict__ pooled, const float* __restrict__ Wl,
    const float* __restrict__ bl, float* __restrict__ out)
{
    int t = blockIdx.x * 256 + threadIdx.x;
    if (t >= NG * OUTC) return;
    int g = t / OUTC, o = t % OUTC;
    float acc = bl[o];
    #pragma unroll
    for (int k = 0; k < HD; k++)
        acc = fmaf(pooled[g * HD + k], Wl[k * OUTC + o], acc);
    out[t] = acc;
}

extern "C" void kernel_launch(void* const* d_in, const int* in_sizes, int n_in,
                              void* d_out, int out_size, void* d_ws, size_t ws_size,
                              hipStream_t stream) {
    const float* x     = (const float*)d_in[0];
    const int*   ei    = (const int*)d_in[1];
    const int*   batch = (const int*)d_in[2];
    const float* W1    = (const float*)d_in[3];
    const float* as1   = (const float*)d_in[4];
    const float* ad1   = (const float*)d_in[5];
    const float* b1    = (const float*)d_in[6];
    const float* W2    = (const float*)d_in[7];
    const float* as2   = (const float*)d_in[8];
    const float* ad2   = (const float*)d_in[9];
    const float* b2    = (const float*)d_in[10];
    const float* Wl    = (const float*)d_in[11];
    const float* bl    = (const float*)d_in[12];
    float* out = (float*)d_out;

    char* w = (char*)d_ws;
    size_t off = 0;
    auto alloc = [&](size_t bytes) {
        void* p = (void*)(w + off);
        off = (off + bytes + 255) & ~(size_t)255;
        return p;
    };
    // zero-initialized block first (deg + cursor)
    int* deg    = (int*)alloc((size_t)NN * 4);
    int* cursor = (int*)alloc((size_t)NN * 4);
    size_t zbytes = off;
    int* rowptr = (int*)alloc((size_t)(NN + 1) * 4);
    int* eidx   = (int*)alloc((size_t)NET * 4);
    unsigned short* xp1 = (unsigned short*)alloc((size_t)NN * FH1 * 2);
    unsigned short* h1  = (unsigned short*)alloc((size_t)NN * FH1 * 2);
    float* s1  = (float*)alloc((size_t)NN * 4 * 4);
    float* d1s = (float*)alloc((size_t)NN * 4 * 4);
    float* xp2 = (float*)alloc((size_t)NN * HD * 4);
    float* s2  = (float*)alloc((size_t)NN * 4);
    float* d2s = (float*)alloc((size_t)NN * 4);
    float* h2  = (float*)alloc((size_t)NN * HD * 4);
    float* pooled = (float*)alloc((size_t)NG * HD * 4);

    hipMemsetAsync(d_ws, 0, zbytes, stream);

    // CSR build (independent of gemm1; same stream serializes fine)
    k_hist   <<<(NET + 255) / 256, 256, 0, stream>>>(ei, deg);
    k_scan   <<<1, 256, 0, stream>>>(deg, rowptr);
    k_scatter<<<(NET + 255) / 256, 256, 0, stream>>>(ei, rowptr, cursor, eidx);

    k_gemm1<<<(NN + 15) / 16, 256, 0, stream>>>(x, W1, as1, ad1, xp1, s1, d1s);
    k_pull1<<<(NN + 3) / 4, 256, 0, stream>>>(rowptr, eidx, s1, d1s, xp1, b1, h1);
    k_gemm2<<<(NN + 15) / 16, 256, 0, stream>>>(h1, W2, as2, ad2, xp2, s2, d2s);
    k_pull2<<<(NN + 3) / 4, 256, 0, stream>>>(rowptr, eidx, s2, d2s, xp2, b2, h2);
    k_pool <<<NG, 256, 0, stream>>>(h2, batch, pooled);
    k_final<<<(NG * OUTC + 255) / 256, 256, 0, stream>>>(pooled, Wl, bl, out);
}

// Round 4
// 481.766 us; speedup vs baseline: 8.3413x; 1.1820x over previous
//
#include <hip/hip_runtime.h>
#include <hip/hip_bf16.h>
#include <cstdint>

#define NN   50000      // nodes
#define NE   800000     // edges (without self loops)
#define NET  850000     // edges + self loops
#define FIN  128
#define FH1  256        // heads*C layer1
#define HD   64
#define NG   64
#define OUTC 10

__device__ __forceinline__ float bf2f(unsigned short u) {
    union { unsigned int i; float f; } v; v.i = ((unsigned int)u) << 16; return v.f;
}
__device__ __forceinline__ unsigned short f2bf(float f) {
    union { float fl; unsigned int i; } v; v.fl = f;
    unsigned int x = v.i;
    return (unsigned short)((x + 0x7FFFu + ((x >> 16) & 1u)) >> 16);
}
__device__ __forceinline__ float leakyr(float v) { return v > 0.f ? v : 0.2f * v; }
__device__ __forceinline__ float elu1(float v)  { return v > 0.f ? v : expm1f(v); }

// ---------------- K1: xp1 = x @ W1 (bf16 out) + scores s1,d1 ----------------
__global__ __launch_bounds__(256) void k_gemm1(
    const float* __restrict__ x, const float* __restrict__ W1,
    const float* __restrict__ asrc, const float* __restrict__ adst,
    unsigned short* __restrict__ xp1, float* __restrict__ s1, float* __restrict__ d1)
{
    __shared__ float xs[16][FIN];
    int row0 = blockIdx.x * 16;
    int tid = threadIdx.x;
    {
        int r = tid >> 4;              // 0..15
        int k = (tid & 15) * 8;        // 0..120
        int gr = row0 + r;
        if (gr < NN) {
            const float4* p = reinterpret_cast<const float4*>(x + (size_t)gr * FIN + k);
            *reinterpret_cast<float4*>(&xs[r][k])     = p[0];
            *reinterpret_cast<float4*>(&xs[r][k + 4]) = p[1];
        } else {
            #pragma unroll
            for (int j = 0; j < 8; j++) xs[r][k + j] = 0.f;
        }
    }
    __syncthreads();
    int c = tid;                        // 0..255 output column
    float acc[16];
    #pragma unroll
    for (int r = 0; r < 16; r++) acc[r] = 0.f;
    for (int k = 0; k < FIN; k += 4) {
        float w0 = W1[(size_t)(k + 0) * FH1 + c];
        float w1 = W1[(size_t)(k + 1) * FH1 + c];
        float w2 = W1[(size_t)(k + 2) * FH1 + c];
        float w3 = W1[(size_t)(k + 3) * FH1 + c];
        #pragma unroll
        for (int r = 0; r < 16; r++) {
            float4 xv = *reinterpret_cast<const float4*>(&xs[r][k]);
            acc[r] = fmaf(xv.x, w0, acc[r]);
            acc[r] = fmaf(xv.y, w1, acc[r]);
            acc[r] = fmaf(xv.z, w2, acc[r]);
            acc[r] = fmaf(xv.w, w3, acc[r]);
        }
    }
    float as = asrc[c], ad = adst[c];
    int head = c >> 6;                  // wave id == head
    int lane = tid & 63;
    #pragma unroll
    for (int r = 0; r < 16; r++) {
        int gr = row0 + r;
        if (gr < NN) xp1[(size_t)gr * FH1 + c] = f2bf(acc[r]);
        float sv = acc[r] * as, dv = acc[r] * ad;
        #pragma unroll
        for (int off = 32; off >= 1; off >>= 1) {
            sv += __shfl_xor(sv, off);
            dv += __shfl_xor(dv, off);
        }
        if (lane == 0 && gr < NN) { s1[gr * 4 + head] = sv; d1[gr * 4 + head] = dv; }
    }
}

// ---------------- CSR build: histogram of dst ----------------
__global__ __launch_bounds__(256) void k_hist(
    const int* __restrict__ ei, int* __restrict__ deg)
{
    int e = blockIdx.x * 256 + threadIdx.x;
    if (e >= NET) return;
    int dst = (e < NE) ? ei[NE + e] : (e - NE);
    atomicAdd(&deg[dst], 1);
}

// ---------------- CSR build: exclusive scan deg -> rowptr (single block) ----------------
__global__ __launch_bounds__(256) void k_scan(
    const int* __restrict__ deg, int* __restrict__ rowptr)
{
    __shared__ int part[256];
    const int CH = (NN + 255) / 256;   // 196 elements per thread
    int t = threadIdx.x;
    int base = t * CH;
    int s = 0;
    for (int i = 0; i < CH; i++) {
        int idx = base + i;
        if (idx < NN) s += deg[idx];
    }
    part[t] = s;
    __syncthreads();
    // Hillis-Steele inclusive scan of part[]
    for (int off = 1; off < 256; off <<= 1) {
        int v = (t >= off) ? part[t - off] : 0;
        __syncthreads();
        part[t] += v;
        __syncthreads();
    }
    int run = part[t] - s;             // exclusive prefix of this thread's chunk
    for (int i = 0; i < CH; i++) {
        int idx = base + i;
        if (idx < NN) { rowptr[idx] = run; run += deg[idx]; }
    }
    if (t == 0) rowptr[NN] = NET;
}

// ---------------- CSR build: scatter edge srcs into slots ----------------
__global__ __launch_bounds__(256) void k_scatter(
    const int* __restrict__ ei, const int* __restrict__ rowptr,
    int* __restrict__ cursor, int* __restrict__ eidx)
{
    int e = blockIdx.x * 256 + threadIdx.x;
    if (e >= NET) return;
    int src, dst;
    if (e < NE) { src = ei[e]; dst = ei[NE + e]; }
    else        { src = dst = e - NE; }
    int pos = atomicAdd(&cursor[dst], 1);
    eidx[rowptr[dst] + pos] = src;
}

// ---------------- K3': layer-1 pull, 4-way unrolled MLP ----------------
__global__ __launch_bounds__(256) void k_pull1(
    const int* __restrict__ rowptr, const int* __restrict__ eidx,
    const float* __restrict__ s1, const float* __restrict__ d1,
    const unsigned short* __restrict__ xp1, const float* __restrict__ b1,
    unsigned short* __restrict__ h1)
{
    int wv = threadIdx.x >> 6;
    int lane = threadIdx.x & 63;
    int n = blockIdx.x * 4 + wv;
    if (n >= NN) return;
    int head = lane >> 4;                  // 16 lanes per head
    int c0 = lane * 4;                     // 4 consecutive cols per lane
    float dv = d1[(size_t)n * 4 + head];
    int jb = rowptr[n], je = rowptr[n + 1];
    float a0 = 0.f, a1 = 0.f, a2 = 0.f, a3 = 0.f;
    float den = 0.f;
    int j = jb;
    for (; j + 4 <= je; j += 4) {
        int sA = eidx[j + 0], sB = eidx[j + 1], sC = eidx[j + 2], sD = eidx[j + 3];
        float scA = s1[(size_t)sA * 4 + head];
        float scB = s1[(size_t)sB * 4 + head];
        float scC = s1[(size_t)sC * 4 + head];
        float scD = s1[(size_t)sD * 4 + head];
        ushort4 xA = *reinterpret_cast<const ushort4*>(xp1 + (size_t)sA * FH1 + c0);
        ushort4 xB = *reinterpret_cast<const ushort4*>(xp1 + (size_t)sB * FH1 + c0);
        ushort4 xC = *reinterpret_cast<const ushort4*>(xp1 + (size_t)sC * FH1 + c0);
        ushort4 xD = *reinterpret_cast<const ushort4*>(xp1 + (size_t)sD * FH1 + c0);
        float eA = __expf(leakyr(scA + dv));
        float eB = __expf(leakyr(scB + dv));
        float eC = __expf(leakyr(scC + dv));
        float eD = __expf(leakyr(scD + dv));
        a0 = fmaf(bf2f(xA.x), eA, a0); a1 = fmaf(bf2f(xA.y), eA, a1);
        a2 = fmaf(bf2f(xA.z), eA, a2); a3 = fmaf(bf2f(xA.w), eA, a3);
        a0 = fmaf(bf2f(xB.x), eB, a0); a1 = fmaf(bf2f(xB.y), eB, a1);
        a2 = fmaf(bf2f(xB.z), eB, a2); a3 = fmaf(bf2f(xB.w), eB, a3);
        a0 = fmaf(bf2f(xC.x), eC, a0); a1 = fmaf(bf2f(xC.y), eC, a1);
        a2 = fmaf(bf2f(xC.z), eC, a2); a3 = fmaf(bf2f(xC.w), eC, a3);
        a0 = fmaf(bf2f(xD.x), eD, a0); a1 = fmaf(bf2f(xD.y), eD, a1);
        a2 = fmaf(bf2f(xD.z), eD, a2); a3 = fmaf(bf2f(xD.w), eD, a3);
        den += (eA + eB) + (eC + eD);
    }
    for (; j < je; j++) {
        int src = eidx[j];
        float ex = __expf(leakyr(s1[(size_t)src * 4 + head] + dv));
        ushort4 xv = *reinterpret_cast<const ushort4*>(xp1 + (size_t)src * FH1 + c0);
        a0 = fmaf(bf2f(xv.x), ex, a0);
        a1 = fmaf(bf2f(xv.y), ex, a1);
        a2 = fmaf(bf2f(xv.z), ex, a2);
        a3 = fmaf(bf2f(xv.w), ex, a3);
        den += ex;
    }
    float inv = 1.0f / den;
    float4 b = *reinterpret_cast<const float4*>(b1 + c0);
    ushort4 st;
    st.x = f2bf(elu1(fmaf(a0, inv, b.x)));
    st.y = f2bf(elu1(fmaf(a1, inv, b.y)));
    st.z = f2bf(elu1(fmaf(a2, inv, b.z)));
    st.w = f2bf(elu1(fmaf(a3, inv, b.w)));
    *reinterpret_cast<ushort4*>(h1 + (size_t)n * FH1 + c0) = st;
}

// ---------------- K5: xp2 = h1 @ W2 (bf16 out) + scores s2,d2 ----------------
__global__ __launch_bounds__(256) void k_gemm2(
    const unsigned short* __restrict__ h1, const float* __restrict__ W2,
    const float* __restrict__ asrc2, const float* __restrict__ adst2,
    unsigned short* __restrict__ xp2, float* __restrict__ s2, float* __restrict__ d2)
{
    __shared__ unsigned short hs[16][FH1];
    int row0 = blockIdx.x * 16;
    int tid = threadIdx.x;
    {
        int lr = tid >> 4;             // 0..15
        int k = (tid & 15) * 16;       // 16 ushorts each (two uint4 loads)
        int gr = row0 + lr;
        uint4 v0 = make_uint4(0, 0, 0, 0);
        uint4 v1 = make_uint4(0, 0, 0, 0);
        if (gr < NN) {
            const uint4* p = reinterpret_cast<const uint4*>(h1 + (size_t)gr * FH1 + k);
            v0 = p[0];
            v1 = p[1];
        }
        *reinterpret_cast<uint4*>(&hs[lr][k])     = v0;
        *reinterpret_cast<uint4*>(&hs[lr][k + 8]) = v1;
    }
    __syncthreads();
    int c = tid & 63;
    int rg = tid >> 6;                  // 4 row groups
    float acc[4] = {0.f, 0.f, 0.f, 0.f};
    for (int k = 0; k < FH1; k += 8) {
        float w[8];
        #pragma unroll
        for (int j = 0; j < 8; j++) w[j] = W2[(size_t)(k + j) * HD + c];
        #pragma unroll
        for (int rr = 0; rr < 4; rr++) {
            int lr = rg * 4 + rr;
            unsigned short xs8[8];
            *reinterpret_cast<uint4*>(xs8) = *reinterpret_cast<const uint4*>(&hs[lr][k]);
            float a = acc[rr];
            #pragma unroll
            for (int j = 0; j < 8; j++) a = fmaf(bf2f(xs8[j]), w[j], a);
            acc[rr] = a;
        }
    }
    float as = asrc2[c], ad = adst2[c];
    int lane = tid & 63;
    #pragma unroll
    for (int rr = 0; rr < 4; rr++) {
        int gr = row0 + rg * 4 + rr;
        if (gr < NN) xp2[(size_t)gr * HD + c] = f2bf(acc[rr]);
        float sv = acc[rr] * as, dv = acc[rr] * ad;
        #pragma unroll
        for (int off = 32; off >= 1; off >>= 1) {
            sv += __shfl_xor(sv, off);
            dv += __shfl_xor(dv, off);
        }
        if (lane == 0 && gr < NN) { s2[gr] = sv; d2[gr] = dv; }
    }
}

// ---------------- K7': layer-2 pull, 4-way unrolled MLP ----------------
__global__ __launch_bounds__(256) void k_pull2(
    const int* __restrict__ rowptr, const int* __restrict__ eidx,
    const float* __restrict__ s2, const float* __restrict__ d2,
    const unsigned short* __restrict__ xp2, const float* __restrict__ b2,
    float* __restrict__ h2)
{
    int wv = threadIdx.x >> 6;
    int lane = threadIdx.x & 63;
    int n = blockIdx.x * 4 + wv;
    if (n >= NN) return;
    float dv = d2[n];
    int jb = rowptr[n], je = rowptr[n + 1];
    float acc = 0.f, den = 0.f;
    int j = jb;
    for (; j + 4 <= je; j += 4) {
        int sA = eidx[j + 0], sB = eidx[j + 1], sC = eidx[j + 2], sD = eidx[j + 3];
        float scA = s2[sA], scB = s2[sB], scC = s2[sC], scD = s2[sD];
        unsigned short xA = xp2[(size_t)sA * HD + lane];
        unsigned short xB = xp2[(size_t)sB * HD + lane];
        unsigned short xC = xp2[(size_t)sC * HD + lane];
        unsigned short xD = xp2[(size_t)sD * HD + lane];
        float eA = __expf(leakyr(scA + dv));
        float eB = __expf(leakyr(scB + dv));
        float eC = __expf(leakyr(scC + dv));
        float eD = __expf(leakyr(scD + dv));
        acc = fmaf(bf2f(xA), eA, acc);
        acc = fmaf(bf2f(xB), eB, acc);
        acc = fmaf(bf2f(xC), eC, acc);
        acc = fmaf(bf2f(xD), eD, acc);
        den += (eA + eB) + (eC + eD);
    }
    for (; j < je; j++) {
        int src = eidx[j];
        float ex = __expf(leakyr(s2[src] + dv));
        acc = fmaf(bf2f(xp2[(size_t)src * HD + lane]), ex, acc);
        den += ex;
    }
    h2[(size_t)n * HD + lane] = elu1(acc / den + b2[lane]);
}

// ---------------- K8: per-graph mean pool of h2 ----------------
__global__ __launch_bounds__(256) void k_pool(
    const float* __restrict__ h2, const int* __restrict__ batch,
    float* __restrict__ pooled)
{
    int g = blockIdx.x;
    int lo = 0, hi = NN;
    while (lo < hi) { int m = (lo + hi) >> 1; if (batch[m] < g) lo = m + 1; else hi = m; }
    int start = lo;
    hi = NN;
    while (lo < hi) { int m = (lo + hi) >> 1; if (batch[m] < g + 1) lo = m + 1; else hi = m; }
    int end = lo;
    int c = threadIdx.x & 63;
    int rg = threadIdx.x >> 6;
    float sum = 0.f;
    for (int n = start + rg; n < end; n += 4)
        sum += h2[(size_t)n * HD + c];
    __shared__ float red[4][64];
    red[rg][c] = sum;
    __syncthreads();
    if (threadIdx.x < 64) {
        float tot = red[0][c] + red[1][c] + red[2][c] + red[3][c];
        float cnt = (float)(end - start);
        pooled[g * HD + c] = tot / fmaxf(cnt, 1.f);
    }
}

// ---------------- K9: final linear [64,64]@[64,10]+bl ----------------
__global__ __launch_bounds__(256) void k_final(
    const float* __restrict__ pooled, const float* __restrict__ Wl,
    const float* __restrict__ bl, float* __restrict__ out)
{
    int t = blockIdx.x * 256 + threadIdx.x;
    if (t >= NG * OUTC) return;
    int g = t / OUTC, o = t % OUTC;
    float acc = bl[o];
    #pragma unroll
    for (int k = 0; k < HD; k++)
        acc = fmaf(pooled[g * HD + k], Wl[k * OUTC + o], acc);
    out[t] = acc;
}

extern "C" void kernel_launch(void* const* d_in, const int* in_sizes, int n_in,
                              void* d_out, int out_size, void* d_ws, size_t ws_size,
                              hipStream_t stream) {
    const float* x     = (const float*)d_in[0];
    const int*   ei    = (const int*)d_in[1];
    const int*   batch = (const int*)d_in[2];
    const float* W1    = (const float*)d_in[3];
    const float* as1   = (const float*)d_in[4];
    const float* ad1   = (const float*)d_in[5];
    const float* b1    = (const float*)d_in[6];
    const float* W2    = (const float*)d_in[7];
    const float* as2   = (const float*)d_in[8];
    const float* ad2   = (const float*)d_in[9];
    const float* b2    = (const float*)d_in[10];
    const float* Wl    = (const float*)d_in[11];
    const float* bl    = (const float*)d_in[12];
    float* out = (float*)d_out;

    char* w = (char*)d_ws;
    size_t off = 0;
    auto alloc = [&](size_t bytes) {
        void* p = (void*)(w + off);
        off = (off + bytes + 255) & ~(size_t)255;
        return p;
    };
    // zero-initialized block first (deg + cursor)
    int* deg    = (int*)alloc((size_t)NN * 4);
    int* cursor = (int*)alloc((size_t)NN * 4);
    size_t zbytes = off;
    int* rowptr = (int*)alloc((size_t)(NN + 1) * 4);
    int* eidx   = (int*)alloc((size_t)NET * 4);
    unsigned short* xp1 = (unsigned short*)alloc((size_t)NN * FH1 * 2);
    unsigned short* h1  = (unsigned short*)alloc((size_t)NN * FH1 * 2);
    float* s1  = (float*)alloc((size_t)NN * 4 * 4);
    float* d1s = (float*)alloc((size_t)NN * 4 * 4);
    unsigned short* xp2 = (unsigned short*)alloc((size_t)NN * HD * 2);
    float* s2  = (float*)alloc((size_t)NN * 4);
    float* d2s = (float*)alloc((size_t)NN * 4);
    float* h2  = (float*)alloc((size_t)NN * HD * 4);
    float* pooled = (float*)alloc((size_t)NG * HD * 4);

    hipMemsetAsync(d_ws, 0, zbytes, stream);

    // CSR build (independent of gemm1; same stream serializes fine)
    k_hist   <<<(NET + 255) / 256, 256, 0, stream>>>(ei, deg);
    k_scan   <<<1, 256, 0, stream>>>(deg, rowptr);
    k_scatter<<<(NET + 255) / 256, 256, 0, stream>>>(ei, rowptr, cursor, eidx);

    k_gemm1<<<(NN + 15) / 16, 256, 0, stream>>>(x, W1, as1, ad1, xp1, s1, d1s);
    k_pull1<<<(NN + 3) / 4, 256, 0, stream>>>(rowptr, eidx, s1, d1s, xp1, b1, h1);
    k_gemm2<<<(NN + 15) / 16, 256, 0, stream>>>(h1, W2, as2, ad2, xp2, s2, d2s);
    k_pull2<<<(NN + 3) / 4, 256, 0, stream>>>(rowptr, eidx, s2, d2s, xp2, b2, h2);
    k_pool <<<NG, 256, 0, stream>>>(h2, batch, pooled);
    k_final<<<(NG * OUTC + 255) / 256, 256, 0, stream>>>(pooled, Wl, bl, out);
}

// Round 5
// 340.411 us; speedup vs baseline: 11.8050x; 1.4152x over previous
//
#include <hip/hip_runtime.h>
#include <hip/hip_bf16.h>
#include <cstdint>

#define NN   50000      // nodes
#define NE   800000     // edges (without self loops)
#define NET  850000     // edges + self loops
#define FIN  128
#define FH1  256        // heads*C layer1
#define HD   64
#define NG   64
#define OUTC 10
#define NBS  ((NN + 255) / 256)   // 196 scan blocks

__device__ __forceinline__ float bf2f(unsigned short u) {
    union { unsigned int i; float f; } v; v.i = ((unsigned int)u) << 16; return v.f;
}
__device__ __forceinline__ unsigned short f2bf(float f) {
    union { float fl; unsigned int i; } v; v.fl = f;
    unsigned int x = v.i;
    return (unsigned short)((x + 0x7FFFu + ((x >> 16) & 1u)) >> 16);
}
__device__ __forceinline__ float leakyr(float v) { return v > 0.f ? v : 0.2f * v; }
__device__ __forceinline__ float elu1(float v)  { return v > 0.f ? v : expm1f(v); }

// ---------------- K1: xp1 = x @ W1 (bf16 out) + scores s1,d1 ----------------
// grid (ceil(NN/64), 4 heads); block 256 = 16x16; 4x4 acc per thread.
__global__ __launch_bounds__(256) void k_gemm1(
    const float* __restrict__ x, const float* __restrict__ W1,
    const float* __restrict__ asrc, const float* __restrict__ adst,
    unsigned short* __restrict__ xp1, float* __restrict__ s1, float* __restrict__ d1)
{
    __shared__ float At[16][68];   // x^T tile (pad 68 -> 272B rows, 16B aligned)
    __shared__ float Bt[16][64];   // W1 tile
    int row0 = blockIdx.x * 64;
    int head = blockIdx.y;
    int n0   = head * 64;
    int tid = threadIdx.x;
    int tx = tid & 15, ty = tid >> 4;
    int lr = tid >> 2, lq = tid & 3;         // staging: row 0..63, quad 0..3
    float acc[4][4] = {};
    for (int k0 = 0; k0 < FIN; k0 += 16) {
        int gr = row0 + lr;
        float4 xv = make_float4(0.f, 0.f, 0.f, 0.f);
        if (gr < NN) xv = *reinterpret_cast<const float4*>(x + (size_t)gr * FIN + k0 + lq * 4);
        At[lq * 4 + 0][lr] = xv.x;
        At[lq * 4 + 1][lr] = xv.y;
        At[lq * 4 + 2][lr] = xv.z;
        At[lq * 4 + 3][lr] = xv.w;
        *reinterpret_cast<float4*>(&Bt[ty][tx * 4]) =
            *reinterpret_cast<const float4*>(W1 + (size_t)(k0 + ty) * FH1 + n0 + tx * 4);
        __syncthreads();
        #pragma unroll
        for (int k = 0; k < 16; k++) {
            float a[4], b[4];
            *reinterpret_cast<float4*>(a) = *reinterpret_cast<const float4*>(&At[k][ty * 4]);
            *reinterpret_cast<float4*>(b) = *reinterpret_cast<const float4*>(&Bt[k][tx * 4]);
            #pragma unroll
            for (int i = 0; i < 4; i++)
                #pragma unroll
                for (int j = 0; j < 4; j++)
                    acc[i][j] = fmaf(a[i], b[j], acc[i][j]);
        }
        __syncthreads();
    }
    float as[4], ad[4];
    #pragma unroll
    for (int j = 0; j < 4; j++) {
        as[j] = asrc[n0 + tx * 4 + j];
        ad[j] = adst[n0 + tx * 4 + j];
    }
    #pragma unroll
    for (int i = 0; i < 4; i++) {
        int row = row0 + ty * 4 + i;
        float sv = acc[i][0] * as[0] + acc[i][1] * as[1] + acc[i][2] * as[2] + acc[i][3] * as[3];
        float dv = acc[i][0] * ad[0] + acc[i][1] * ad[1] + acc[i][2] * ad[2] + acc[i][3] * ad[3];
        #pragma unroll
        for (int off = 8; off >= 1; off >>= 1) {
            sv += __shfl_xor(sv, off, 16);
            dv += __shfl_xor(dv, off, 16);
        }
        if (row < NN) {
            ushort4 st;
            st.x = f2bf(acc[i][0]); st.y = f2bf(acc[i][1]);
            st.z = f2bf(acc[i][2]); st.w = f2bf(acc[i][3]);
            *reinterpret_cast<ushort4*>(xp1 + (size_t)row * FH1 + n0 + tx * 4) = st;
            if (tx == 0) { s1[row * 4 + head] = sv; d1[row * 4 + head] = dv; }
        }
    }
}

// ---------------- CSR build: histogram of dst ----------------
__global__ __launch_bounds__(256) void k_hist(
    const int* __restrict__ ei, int* __restrict__ deg)
{
    int e = blockIdx.x * 256 + threadIdx.x;
    if (e >= NET) return;
    int dst = (e < NE) ? ei[NE + e] : (e - NE);
    atomicAdd(&deg[dst], 1);
}

// ---------------- hierarchical scan: phase A (block sums) ----------------
__global__ __launch_bounds__(256) void k_scan_a(
    const int* __restrict__ deg, int* __restrict__ part)
{
    __shared__ int sm[256];
    int t = threadIdx.x;
    int idx = blockIdx.x * 256 + t;
    sm[t] = (idx < NN) ? deg[idx] : 0;
    __syncthreads();
    for (int off = 128; off >= 1; off >>= 1) {
        if (t < off) sm[t] += sm[t + off];
        __syncthreads();
    }
    if (t == 0) part[blockIdx.x] = sm[0];
}

// ---------------- phase B: scan the 196 partials (1 block) ----------------
__global__ __launch_bounds__(256) void k_scan_b(
    int* __restrict__ part, int* __restrict__ rowptr)
{
    __shared__ int sm[256];
    int t = threadIdx.x;
    int v = (t < NBS) ? part[t] : 0;
    sm[t] = v;
    __syncthreads();
    for (int off = 1; off < 256; off <<= 1) {
        int u = (t >= off) ? sm[t - off] : 0;
        __syncthreads();
        sm[t] += u;
        __syncthreads();
    }
    if (t < NBS) part[t] = sm[t] - v;   // exclusive prefix of block sums
    if (t == 0) rowptr[NN] = NET;
}

// ---------------- phase C: per-block rescan + offset -> rowptr ----------------
__global__ __launch_bounds__(256) void k_scan_c(
    const int* __restrict__ deg, const int* __restrict__ part,
    int* __restrict__ rowptr)
{
    __shared__ int sm[256];
    int t = threadIdx.x;
    int idx = blockIdx.x * 256 + t;
    int v = (idx < NN) ? deg[idx] : 0;
    sm[t] = v;
    __syncthreads();
    for (int off = 1; off < 256; off <<= 1) {
        int u = (t >= off) ? sm[t - off] : 0;
        __syncthreads();
        sm[t] += u;
        __syncthreads();
    }
    if (idx < NN) rowptr[idx] = part[blockIdx.x] + sm[t] - v;
}

// ---------------- CSR build: scatter edge srcs into slots ----------------
__global__ __launch_bounds__(256) void k_scatter(
    const int* __restrict__ ei, const int* __restrict__ rowptr,
    int* __restrict__ cursor, int* __restrict__ eidx)
{
    int e = blockIdx.x * 256 + threadIdx.x;
    if (e >= NET) return;
    int src, dst;
    if (e < NE) { src = ei[e]; dst = ei[NE + e]; }
    else        { src = dst = e - NE; }
    int pos = atomicAdd(&cursor[dst], 1);
    eidx[rowptr[dst] + pos] = src;
}

// ---------------- K3': layer-1 pull, 4-way unrolled MLP ----------------
__global__ __launch_bounds__(256) void k_pull1(
    const int* __restrict__ rowptr, const int* __restrict__ eidx,
    const float* __restrict__ s1, const float* __restrict__ d1,
    const unsigned short* __restrict__ xp1, const float* __restrict__ b1,
    unsigned short* __restrict__ h1)
{
    int wv = threadIdx.x >> 6;
    int lane = threadIdx.x & 63;
    int n = blockIdx.x * 4 + wv;
    if (n >= NN) return;
    int head = lane >> 4;                  // 16 lanes per head
    int c0 = lane * 4;                     // 4 consecutive cols per lane
    float dv = d1[(size_t)n * 4 + head];
    int jb = rowptr[n], je = rowptr[n + 1];
    float a0 = 0.f, a1 = 0.f, a2 = 0.f, a3 = 0.f;
    float den = 0.f;
    int j = jb;
    for (; j + 4 <= je; j += 4) {
        int sA = eidx[j + 0], sB = eidx[j + 1], sC = eidx[j + 2], sD = eidx[j + 3];
        float scA = s1[(size_t)sA * 4 + head];
        float scB = s1[(size_t)sB * 4 + head];
        float scC = s1[(size_t)sC * 4 + head];
        float scD = s1[(size_t)sD * 4 + head];
        ushort4 xA = *reinterpret_cast<const ushort4*>(xp1 + (size_t)sA * FH1 + c0);
        ushort4 xB = *reinterpret_cast<const ushort4*>(xp1 + (size_t)sB * FH1 + c0);
        ushort4 xC = *reinterpret_cast<const ushort4*>(xp1 + (size_t)sC * FH1 + c0);
        ushort4 xD = *reinterpret_cast<const ushort4*>(xp1 + (size_t)sD * FH1 + c0);
        float eA = __expf(leakyr(scA + dv));
        float eB = __expf(leakyr(scB + dv));
        float eC = __expf(leakyr(scC + dv));
        float eD = __expf(leakyr(scD + dv));
        a0 = fmaf(bf2f(xA.x), eA, a0); a1 = fmaf(bf2f(xA.y), eA, a1);
        a2 = fmaf(bf2f(xA.z), eA, a2); a3 = fmaf(bf2f(xA.w), eA, a3);
        a0 = fmaf(bf2f(xB.x), eB, a0); a1 = fmaf(bf2f(xB.y), eB, a1);
        a2 = fmaf(bf2f(xB.z), eB, a2); a3 = fmaf(bf2f(xB.w), eB, a3);
        a0 = fmaf(bf2f(xC.x), eC, a0); a1 = fmaf(bf2f(xC.y), eC, a1);
        a2 = fmaf(bf2f(xC.z), eC, a2); a3 = fmaf(bf2f(xC.w), eC, a3);
        a0 = fmaf(bf2f(xD.x), eD, a0); a1 = fmaf(bf2f(xD.y), eD, a1);
        a2 = fmaf(bf2f(xD.z), eD, a2); a3 = fmaf(bf2f(xD.w), eD, a3);
        den += (eA + eB) + (eC + eD);
    }
    for (; j < je; j++) {
        int src = eidx[j];
        float ex = __expf(leakyr(s1[(size_t)src * 4 + head] + dv));
        ushort4 xv = *reinterpret_cast<const ushort4*>(xp1 + (size_t)src * FH1 + c0);
        a0 = fmaf(bf2f(xv.x), ex, a0);
        a1 = fmaf(bf2f(xv.y), ex, a1);
        a2 = fmaf(bf2f(xv.z), ex, a2);
        a3 = fmaf(bf2f(xv.w), ex, a3);
        den += ex;
    }
    float inv = 1.0f / den;
    float4 b = *reinterpret_cast<const float4*>(b1 + c0);
    ushort4 st;
    st.x = f2bf(elu1(fmaf(a0, inv, b.x)));
    st.y = f2bf(elu1(fmaf(a1, inv, b.y)));
    st.z = f2bf(elu1(fmaf(a2, inv, b.z)));
    st.w = f2bf(elu1(fmaf(a3, inv, b.w)));
    *reinterpret_cast<ushort4*>(h1 + (size_t)n * FH1 + c0) = st;
}

// ---------------- K5: xp2 = h1 @ W2 (bf16 out) + scores s2,d2 ----------------
// grid ceil(NN/64); block 256 = 16x16; 4x4 acc; K=256 (bf16 input).
__global__ __launch_bounds__(256) void k_gemm2(
    const unsigned short* __restrict__ h1, const float* __restrict__ W2,
    const float* __restrict__ asrc2, const float* __restrict__ adst2,
    unsigned short* __restrict__ xp2, float* __restrict__ s2, float* __restrict__ d2)
{
    __shared__ float At[16][68];
    __shared__ float Bt[16][64];
    int row0 = blockIdx.x * 64;
    int tid = threadIdx.x;
    int tx = tid & 15, ty = tid >> 4;
    int lr = tid >> 2, lq = tid & 3;
    float acc[4][4] = {};
    for (int k0 = 0; k0 < FH1; k0 += 16) {
        int gr = row0 + lr;
        ushort4 hv = make_ushort4(0, 0, 0, 0);
        if (gr < NN) hv = *reinterpret_cast<const ushort4*>(h1 + (size_t)gr * FH1 + k0 + lq * 4);
        At[lq * 4 + 0][lr] = bf2f(hv.x);
        At[lq * 4 + 1][lr] = bf2f(hv.y);
        At[lq * 4 + 2][lr] = bf2f(hv.z);
        At[lq * 4 + 3][lr] = bf2f(hv.w);
        *reinterpret_cast<float4*>(&Bt[ty][tx * 4]) =
            *reinterpret_cast<const float4*>(W2 + (size_t)(k0 + ty) * HD + tx * 4);
        __syncthreads();
        #pragma unroll
        for (int k = 0; k < 16; k++) {
            float a[4], b[4];
            *reinterpret_cast<float4*>(a) = *reinterpret_cast<const float4*>(&At[k][ty * 4]);
            *reinterpret_cast<float4*>(b) = *reinterpret_cast<const float4*>(&Bt[k][tx * 4]);
            #pragma unroll
            for (int i = 0; i < 4; i++)
                #pragma unroll
                for (int j = 0; j < 4; j++)
                    acc[i][j] = fmaf(a[i], b[j], acc[i][j]);
        }
        __syncthreads();
    }
    float as[4], ad[4];
    #pragma unroll
    for (int j = 0; j < 4; j++) {
        as[j] = asrc2[tx * 4 + j];
        ad[j] = adst2[tx * 4 + j];
    }
    #pragma unroll
    for (int i = 0; i < 4; i++) {
        int row = row0 + ty * 4 + i;
        float sv = acc[i][0] * as[0] + acc[i][1] * as[1] + acc[i][2] * as[2] + acc[i][3] * as[3];
        float dv = acc[i][0] * ad[0] + acc[i][1] * ad[1] + acc[i][2] * ad[2] + acc[i][3] * ad[3];
        #pragma unroll
        for (int off = 8; off >= 1; off >>= 1) {
            sv += __shfl_xor(sv, off, 16);
            dv += __shfl_xor(dv, off, 16);
        }
        if (row < NN) {
            ushort4 st;
            st.x = f2bf(acc[i][0]); st.y = f2bf(acc[i][1]);
            st.z = f2bf(acc[i][2]); st.w = f2bf(acc[i][3]);
            *reinterpret_cast<ushort4*>(xp2 + (size_t)row * HD + tx * 4) = st;
            if (tx == 0) { s2[row] = sv; d2[row] = dv; }
        }
    }
}

// ---------------- K7': layer-2 pull, 4-way unrolled MLP ----------------
__global__ __launch_bounds__(256) void k_pull2(
    const int* __restrict__ rowptr, const int* __restrict__ eidx,
    const float* __restrict__ s2, const float* __restrict__ d2,
    const unsigned short* __restrict__ xp2, const float* __restrict__ b2,
    float* __restrict__ h2)
{
    int wv = threadIdx.x >> 6;
    int lane = threadIdx.x & 63;
    int n = blockIdx.x * 4 + wv;
    if (n >= NN) return;
    float dv = d2[n];
    int jb = rowptr[n], je = rowptr[n + 1];
    float acc = 0.f, den = 0.f;
    int j = jb;
    for (; j + 4 <= je; j += 4) {
        int sA = eidx[j + 0], sB = eidx[j + 1], sC = eidx[j + 2], sD = eidx[j + 3];
        float scA = s2[sA], scB = s2[sB], scC = s2[sC], scD = s2[sD];
        unsigned short xA = xp2[(size_t)sA * HD + lane];
        unsigned short xB = xp2[(size_t)sB * HD + lane];
        unsigned short xC = xp2[(size_t)sC * HD + lane];
        unsigned short xD = xp2[(size_t)sD * HD + lane];
        float eA = __expf(leakyr(scA + dv));
        float eB = __expf(leakyr(scB + dv));
        float eC = __expf(leakyr(scC + dv));
        float eD = __expf(leakyr(scD + dv));
        acc = fmaf(bf2f(xA), eA, acc);
        acc = fmaf(bf2f(xB), eB, acc);
        acc = fmaf(bf2f(xC), eC, acc);
        acc = fmaf(bf2f(xD), eD, acc);
        den += (eA + eB) + (eC + eD);
    }
    for (; j < je; j++) {
        int src = eidx[j];
        float ex = __expf(leakyr(s2[src] + dv));
        acc = fmaf(bf2f(xp2[(size_t)src * HD + lane]), ex, acc);
        den += ex;
    }
    h2[(size_t)n * HD + lane] = elu1(acc / den + b2[lane]);
}

// ---------------- K8: per-graph mean pool of h2 ----------------
__global__ __launch_bounds__(256) void k_pool(
    const float* __restrict__ h2, const int* __restrict__ batch,
    float* __restrict__ pooled)
{
    int g = blockIdx.x;
    int lo = 0, hi = NN;
    while (lo < hi) { int m = (lo + hi) >> 1; if (batch[m] < g) lo = m + 1; else hi = m; }
    int start = lo;
    hi = NN;
    while (lo < hi) { int m = (lo + hi) >> 1; if (batch[m] < g + 1) lo = m + 1; else hi = m; }
    int end = lo;
    int c = threadIdx.x & 63;
    int rg = threadIdx.x >> 6;
    float sum = 0.f;
    for (int n = start + rg; n < end; n += 4)
        sum += h2[(size_t)n * HD + c];
    __shared__ float red[4][64];
    red[rg][c] = sum;
    __syncthreads();
    if (threadIdx.x < 64) {
        float tot = red[0][c] + red[1][c] + red[2][c] + red[3][c];
        float cnt = (float)(end - start);
        pooled[g * HD + c] = tot / fmaxf(cnt, 1.f);
    }
}

// ---------------- K9: final linear [64,64]@[64,10]+bl ----------------
__global__ __launch_bounds__(256) void k_final(
    const float* __restrict__ pooled, const float* __restrict__ Wl,
    const float* __restrict__ bl, float* __restrict__ out)
{
    int t = blockIdx.x * 256 + threadIdx.x;
    if (t >= NG * OUTC) return;
    int g = t / OUTC, o = t % OUTC;
    float acc = bl[o];
    #pragma unroll
    for (int k = 0; k < HD; k++)
        acc = fmaf(pooled[g * HD + k], Wl[k * OUTC + o], acc);
    out[t] = acc;
}

extern "C" void kernel_launch(void* const* d_in, const int* in_sizes, int n_in,
                              void* d_out, int out_size, void* d_ws, size_t ws_size,
                              hipStream_t stream) {
    const float* x     = (const float*)d_in[0];
    const int*   ei    = (const int*)d_in[1];
    const int*   batch = (const int*)d_in[2];
    const float* W1    = (const float*)d_in[3];
    const float* as1   = (const float*)d_in[4];
    const float* ad1   = (const float*)d_in[5];
    const float* b1    = (const float*)d_in[6];
    const float* W2    = (const float*)d_in[7];
    const float* as2   = (const float*)d_in[8];
    const float* ad2   = (const float*)d_in[9];
    const float* b2    = (const float*)d_in[10];
    const float* Wl    = (const float*)d_in[11];
    const float* bl    = (const float*)d_in[12];
    float* out = (float*)d_out;

    char* w = (char*)d_ws;
    size_t off = 0;
    auto alloc = [&](size_t bytes) {
        void* p = (void*)(w + off);
        off = (off + bytes + 255) & ~(size_t)255;
        return p;
    };
    // zero-initialized block first (deg + cursor)
    int* deg    = (int*)alloc((size_t)NN * 4);
    int* cursor = (int*)alloc((size_t)NN * 4);
    size_t zbytes = off;
    int* part   = (int*)alloc((size_t)NBS * 4);
    int* rowptr = (int*)alloc((size_t)(NN + 1) * 4);
    int* eidx   = (int*)alloc((size_t)NET * 4);
    unsigned short* xp1 = (unsigned short*)alloc((size_t)NN * FH1 * 2);
    unsigned short* h1  = (unsigned short*)alloc((size_t)NN * FH1 * 2);
    float* s1  = (float*)alloc((size_t)NN * 4 * 4);
    float* d1s = (float*)alloc((size_t)NN * 4 * 4);
    unsigned short* xp2 = (unsigned short*)alloc((size_t)NN * HD * 2);
    float* s2  = (float*)alloc((size_t)NN * 4);
    float* d2s = (float*)alloc((size_t)NN * 4);
    float* h2  = (float*)alloc((size_t)NN * HD * 4);
    float* pooled = (float*)alloc((size_t)NG * HD * 4);

    hipMemsetAsync(d_ws, 0, zbytes, stream);

    // CSR build
    k_hist   <<<(NET + 255) / 256, 256, 0, stream>>>(ei, deg);
    k_scan_a <<<NBS, 256, 0, stream>>>(deg, part);
    k_scan_b <<<1, 256, 0, stream>>>(part, rowptr);
    k_scan_c <<<NBS, 256, 0, stream>>>(deg, part, rowptr);
    k_scatter<<<(NET + 255) / 256, 256, 0, stream>>>(ei, rowptr, cursor, eidx);

    dim3 g1((NN + 63) / 64, 4);
    k_gemm1<<<g1, 256, 0, stream>>>(x, W1, as1, ad1, xp1, s1, d1s);
    k_pull1<<<(NN + 3) / 4, 256, 0, stream>>>(rowptr, eidx, s1, d1s, xp1, b1, h1);
    k_gemm2<<<(NN + 63) / 64, 256, 0, stream>>>(h1, W2, as2, ad2, xp2, s2, d2s);
    k_pull2<<<(NN + 3) / 4, 256, 0, stream>>>(rowptr, eidx, s2, d2s, xp2, b2, h2);
    k_pool <<<NG, 256, 0, stream>>>(h2, batch, pooled);
    k_final<<<(NG * OUTC + 255) / 256, 256, 0, stream>>>(pooled, Wl, bl, out);
}

// Round 6
// 339.181 us; speedup vs baseline: 11.8477x; 1.0036x over previous
//
#include <hip/hip_runtime.h>
#include <hip/hip_bf16.h>
#include <cstdint>

#define NN   50000      // nodes
#define NE   800000     // edges (without self loops)
#define NET  850000     // edges + self loops
#define FIN  128
#define FH1  256        // heads*C layer1
#define HD   64
#define NG   64
#define OUTC 10
#define NBS  ((NN + 255) / 256)   // 196 scan blocks

__device__ __forceinline__ float bf2f(unsigned short u) {
    union { unsigned int i; float f; } v; v.i = ((unsigned int)u) << 16; return v.f;
}
__device__ __forceinline__ float bflo(unsigned int u) {
    union { unsigned int i; float f; } v; v.i = u << 16; return v.f;
}
__device__ __forceinline__ float bfhi(unsigned int u) {
    union { unsigned int i; float f; } v; v.i = u & 0xFFFF0000u; return v.f;
}
__device__ __forceinline__ unsigned short f2bf(float f) {
    union { float fl; unsigned int i; } v; v.fl = f;
    unsigned int x = v.i;
    return (unsigned short)((x + 0x7FFFu + ((x >> 16) & 1u)) >> 16);
}
__device__ __forceinline__ float leakyr(float v) { return v > 0.f ? v : 0.2f * v; }
__device__ __forceinline__ float elu1(float v)  { return v > 0.f ? v : expm1f(v); }

// ---------------- K1: xp1 = x @ W1 (bf16 out) + scores s1t (transposed), d1 ----------------
// grid (ceil(NN/64), 4 heads); block 256 = 16x16; 4x4 acc per thread.
__global__ __launch_bounds__(256) void k_gemm1(
    const float* __restrict__ x, const float* __restrict__ W1,
    const float* __restrict__ asrc, const float* __restrict__ adst,
    unsigned short* __restrict__ xp1, float* __restrict__ s1t, float* __restrict__ d1)
{
    __shared__ float At[16][68];   // x^T tile (pad 68 -> 272B rows, 16B aligned)
    __shared__ float Bt[16][64];   // W1 tile
    int row0 = blockIdx.x * 64;
    int head = blockIdx.y;
    int n0   = head * 64;
    int tid = threadIdx.x;
    int tx = tid & 15, ty = tid >> 4;
    int lr = tid >> 2, lq = tid & 3;         // staging: row 0..63, quad 0..3
    float acc[4][4] = {};
    for (int k0 = 0; k0 < FIN; k0 += 16) {
        int gr = row0 + lr;
        float4 xv = make_float4(0.f, 0.f, 0.f, 0.f);
        if (gr < NN) xv = *reinterpret_cast<const float4*>(x + (size_t)gr * FIN + k0 + lq * 4);
        At[lq * 4 + 0][lr] = xv.x;
        At[lq * 4 + 1][lr] = xv.y;
        At[lq * 4 + 2][lr] = xv.z;
        At[lq * 4 + 3][lr] = xv.w;
        *reinterpret_cast<float4*>(&Bt[ty][tx * 4]) =
            *reinterpret_cast<const float4*>(W1 + (size_t)(k0 + ty) * FH1 + n0 + tx * 4);
        __syncthreads();
        #pragma unroll
        for (int k = 0; k < 16; k++) {
            float a[4], b[4];
            *reinterpret_cast<float4*>(a) = *reinterpret_cast<const float4*>(&At[k][ty * 4]);
            *reinterpret_cast<float4*>(b) = *reinterpret_cast<const float4*>(&Bt[k][tx * 4]);
            #pragma unroll
            for (int i = 0; i < 4; i++)
                #pragma unroll
                for (int j = 0; j < 4; j++)
                    acc[i][j] = fmaf(a[i], b[j], acc[i][j]);
        }
        __syncthreads();
    }
    float as[4], ad[4];
    #pragma unroll
    for (int j = 0; j < 4; j++) {
        as[j] = asrc[n0 + tx * 4 + j];
        ad[j] = adst[n0 + tx * 4 + j];
    }
    #pragma unroll
    for (int i = 0; i < 4; i++) {
        int row = row0 + ty * 4 + i;
        float sv = acc[i][0] * as[0] + acc[i][1] * as[1] + acc[i][2] * as[2] + acc[i][3] * as[3];
        float dv = acc[i][0] * ad[0] + acc[i][1] * ad[1] + acc[i][2] * ad[2] + acc[i][3] * ad[3];
        #pragma unroll
        for (int off = 8; off >= 1; off >>= 1) {
            sv += __shfl_xor(sv, off, 16);
            dv += __shfl_xor(dv, off, 16);
        }
        if (row < NN) {
            ushort4 st;
            st.x = f2bf(acc[i][0]); st.y = f2bf(acc[i][1]);
            st.z = f2bf(acc[i][2]); st.w = f2bf(acc[i][3]);
            *reinterpret_cast<ushort4*>(xp1 + (size_t)row * FH1 + n0 + tx * 4) = st;
            if (tx == 0) { s1t[(size_t)head * NN + row] = sv; d1[row * 4 + head] = dv; }
        }
    }
}

// ---------------- CSR build: histogram of dst ----------------
__global__ __launch_bounds__(256) void k_hist(
    const int* __restrict__ ei, int* __restrict__ deg)
{
    int e = blockIdx.x * 256 + threadIdx.x;
    if (e >= NET) return;
    int dst = (e < NE) ? ei[NE + e] : (e - NE);
    atomicAdd(&deg[dst], 1);
}

// ---------------- hierarchical scan: phase A (block sums) ----------------
__global__ __launch_bounds__(256) void k_scan_a(
    const int* __restrict__ deg, int* __restrict__ part)
{
    __shared__ int sm[256];
    int t = threadIdx.x;
    int idx = blockIdx.x * 256 + t;
    sm[t] = (idx < NN) ? deg[idx] : 0;
    __syncthreads();
    for (int off = 128; off >= 1; off >>= 1) {
        if (t < off) sm[t] += sm[t + off];
        __syncthreads();
    }
    if (t == 0) part[blockIdx.x] = sm[0];
}

// ---------------- phase B: scan the 196 partials (1 block) ----------------
__global__ __launch_bounds__(256) void k_scan_b(
    int* __restrict__ part, int* __restrict__ rowptr)
{
    __shared__ int sm[256];
    int t = threadIdx.x;
    int v = (t < NBS) ? part[t] : 0;
    sm[t] = v;
    __syncthreads();
    for (int off = 1; off < 256; off <<= 1) {
        int u = (t >= off) ? sm[t - off] : 0;
        __syncthreads();
        sm[t] += u;
        __syncthreads();
    }
    if (t < NBS) part[t] = sm[t] - v;   // exclusive prefix of block sums
    if (t == 0) rowptr[NN] = NET;
}

// ---------------- phase C: per-block rescan + offset -> rowptr ----------------
__global__ __launch_bounds__(256) void k_scan_c(
    const int* __restrict__ deg, const int* __restrict__ part,
    int* __restrict__ rowptr)
{
    __shared__ int sm[256];
    int t = threadIdx.x;
    int idx = blockIdx.x * 256 + t;
    int v = (idx < NN) ? deg[idx] : 0;
    sm[t] = v;
    __syncthreads();
    for (int off = 1; off < 256; off <<= 1) {
        int u = (t >= off) ? sm[t - off] : 0;
        __syncthreads();
        sm[t] += u;
        __syncthreads();
    }
    if (idx < NN) rowptr[idx] = part[blockIdx.x] + sm[t] - v;
}

// ---------------- CSR build: scatter edge srcs into slots ----------------
__global__ __launch_bounds__(256) void k_scatter(
    const int* __restrict__ ei, const int* __restrict__ rowptr,
    int* __restrict__ cursor, int* __restrict__ eidx)
{
    int e = blockIdx.x * 256 + threadIdx.x;
    if (e >= NET) return;
    int src, dst;
    if (e < NE) { src = ei[e]; dst = ei[NE + e]; }
    else        { src = dst = e - NE; }
    int pos = atomicAdd(&cursor[dst], 1);
    eidx[rowptr[dst] + pos] = src;
}

// ---------------- K3': layer-1 pull — scalar-pipe addressing, 8-way MLP ----------------
__global__ __launch_bounds__(256) void k_pull1(
    const int* __restrict__ rowptr, const int* __restrict__ eidx,
    const float* __restrict__ s1t, const float* __restrict__ d1,
    const unsigned short* __restrict__ xp1, const float* __restrict__ b1,
    unsigned short* __restrict__ h1)
{
    int wv = threadIdx.x >> 6;
    int lane = threadIdx.x & 63;
    int n = blockIdx.x * 4 + wv;
    if (n >= NN) return;
    int head = lane >> 4;                  // 16 lanes per head
    int c0 = lane * 4;                     // 4 consecutive cols per lane
    int hNN = head * NN;                   // per-lane, loop-invariant score offset
    float dv = d1[(size_t)n * 4 + head];
    // wave-uniform row bounds in SGPRs -> eidx loads become s_load
    int jb = __builtin_amdgcn_readfirstlane(rowptr[n]);
    int je = __builtin_amdgcn_readfirstlane(rowptr[n + 1]);
    float a0 = 0.f, a1 = 0.f, a2 = 0.f, a3 = 0.f;
    float den = 0.f;
    int j = jb;
    for (; j + 8 <= je; j += 8) {
        int s[8];
        #pragma unroll
        for (int q = 0; q < 8; q++) s[q] = eidx[j + q];       // uniform -> s_load
        float sc[8];
        uint2 u[8];
        #pragma unroll
        for (int q = 0; q < 8; q++) {
            const float* srow = s1t + s[q];                   // uniform base
            sc[q] = srow[hNN];                                // + per-lane voffset
            const unsigned short* xrow = xp1 + (size_t)s[q] * FH1;  // uniform base
            u[q] = *reinterpret_cast<const uint2*>(xrow + c0);      // + per-lane voffset
        }
        #pragma unroll
        for (int q = 0; q < 8; q++) {
            float ex = __expf(leakyr(sc[q] + dv));
            a0 = fmaf(bflo(u[q].x), ex, a0);
            a1 = fmaf(bfhi(u[q].x), ex, a1);
            a2 = fmaf(bflo(u[q].y), ex, a2);
            a3 = fmaf(bfhi(u[q].y), ex, a3);
            den += ex;
        }
    }
    for (; j < je; j++) {
        int src = eidx[j];
        const float* srow = s1t + src;
        float ex = __expf(leakyr(srow[hNN] + dv));
        const unsigned short* xrow = xp1 + (size_t)src * FH1;
        uint2 u = *reinterpret_cast<const uint2*>(xrow + c0);
        a0 = fmaf(bflo(u.x), ex, a0);
        a1 = fmaf(bfhi(u.x), ex, a1);
        a2 = fmaf(bflo(u.y), ex, a2);
        a3 = fmaf(bfhi(u.y), ex, a3);
        den += ex;
    }
    // note: a1/a3 hold the *hi* bf16 halves -> columns c0+1/c0+3 pair with bfhi scale
    float inv = 1.0f / den;
    float4 b = *reinterpret_cast<const float4*>(b1 + c0);
    ushort4 st;
    st.x = f2bf(elu1(fmaf(a0, inv, b.x)));
    st.y = f2bf(elu1(fmaf(a1, inv, b.y)));
    st.z = f2bf(elu1(fmaf(a2, inv, b.z)));
    st.w = f2bf(elu1(fmaf(a3, inv, b.w)));
    *reinterpret_cast<ushort4*>(h1 + (size_t)n * FH1 + c0) = st;
}

// ---------------- K5: xp2 = h1 @ W2 (bf16 out) + scores s2,d2 ----------------
// grid ceil(NN/64); block 256 = 16x16; 4x4 acc; K=256 (bf16 input).
__global__ __launch_bounds__(256) void k_gemm2(
    const unsigned short* __restrict__ h1, const float* __restrict__ W2,
    const float* __restrict__ asrc2, const float* __restrict__ adst2,
    unsigned short* __restrict__ xp2, float* __restrict__ s2, float* __restrict__ d2)
{
    __shared__ float At[16][68];
    __shared__ float Bt[16][64];
    int row0 = blockIdx.x * 64;
    int tid = threadIdx.x;
    int tx = tid & 15, ty = tid >> 4;
    int lr = tid >> 2, lq = tid & 3;
    float acc[4][4] = {};
    for (int k0 = 0; k0 < FH1; k0 += 16) {
        int gr = row0 + lr;
        ushort4 hv = make_ushort4(0, 0, 0, 0);
        if (gr < NN) hv = *reinterpret_cast<const ushort4*>(h1 + (size_t)gr * FH1 + k0 + lq * 4);
        At[lq * 4 + 0][lr] = bf2f(hv.x);
        At[lq * 4 + 1][lr] = bf2f(hv.y);
        At[lq * 4 + 2][lr] = bf2f(hv.z);
        At[lq * 4 + 3][lr] = bf2f(hv.w);
        *reinterpret_cast<float4*>(&Bt[ty][tx * 4]) =
            *reinterpret_cast<const float4*>(W2 + (size_t)(k0 + ty) * HD + tx * 4);
        __syncthreads();
        #pragma unroll
        for (int k = 0; k < 16; k++) {
            float a[4], b[4];
            *reinterpret_cast<float4*>(a) = *reinterpret_cast<const float4*>(&At[k][ty * 4]);
            *reinterpret_cast<float4*>(b) = *reinterpret_cast<const float4*>(&Bt[k][tx * 4]);
            #pragma unroll
            for (int i = 0; i < 4; i++)
                #pragma unroll
                for (int j = 0; j < 4; j++)
                    acc[i][j] = fmaf(a[i], b[j], acc[i][j]);
        }
        __syncthreads();
    }
    float as[4], ad[4];
    #pragma unroll
    for (int j = 0; j < 4; j++) {
        as[j] = asrc2[tx * 4 + j];
        ad[j] = adst2[tx * 4 + j];
    }
    #pragma unroll
    for (int i = 0; i < 4; i++) {
        int row = row0 + ty * 4 + i;
        float sv = acc[i][0] * as[0] + acc[i][1] * as[1] + acc[i][2] * as[2] + acc[i][3] * as[3];
        float dv = acc[i][0] * ad[0] + acc[i][1] * ad[1] + acc[i][2] * ad[2] + acc[i][3] * ad[3];
        #pragma unroll
        for (int off = 8; off >= 1; off >>= 1) {
            sv += __shfl_xor(sv, off, 16);
            dv += __shfl_xor(dv, off, 16);
        }
        if (row < NN) {
            ushort4 st;
            st.x = f2bf(acc[i][0]); st.y = f2bf(acc[i][1]);
            st.z = f2bf(acc[i][2]); st.w = f2bf(acc[i][3]);
            *reinterpret_cast<ushort4*>(xp2 + (size_t)row * HD + tx * 4) = st;
            if (tx == 0) { s2[row] = sv; d2[row] = dv; }
        }
    }
}

// ---------------- K7': layer-2 pull — scalar-pipe addressing, 8-way MLP ----------------
__global__ __launch_bounds__(256) void k_pull2(
    const int* __restrict__ rowptr, const int* __restrict__ eidx,
    const float* __restrict__ s2, const float* __restrict__ d2,
    const unsigned short* __restrict__ xp2, const float* __restrict__ b2,
    float* __restrict__ h2)
{
    int wv = threadIdx.x >> 6;
    int lane = threadIdx.x & 63;
    int n = blockIdx.x * 4 + wv;
    if (n >= NN) return;
    float dv = d2[n];
    int jb = __builtin_amdgcn_readfirstlane(rowptr[n]);
    int je = __builtin_amdgcn_readfirstlane(rowptr[n + 1]);
    float acc = 0.f, den = 0.f;
    int j = jb;
    for (; j + 8 <= je; j += 8) {
        int s[8];
        #pragma unroll
        for (int q = 0; q < 8; q++) s[q] = eidx[j + q];       // s_load
        float sc[8];
        unsigned short xv[8];
        #pragma unroll
        for (int q = 0; q < 8; q++) {
            sc[q] = s2[s[q]];                                 // uniform -> s_load
            const unsigned short* xrow = xp2 + (size_t)s[q] * HD;
            xv[q] = xrow[lane];
        }
        #pragma unroll
        for (int q = 0; q < 8; q++) {
            float ex = __expf(leakyr(sc[q] + dv));
            acc = fmaf(bf2f(xv[q]), ex, acc);
            den += ex;
        }
    }
    for (; j < je; j++) {
        int src = eidx[j];
        float ex = __expf(leakyr(s2[src] + dv));
        const unsigned short* xrow = xp2 + (size_t)src * HD;
        acc = fmaf(bf2f(xrow[lane]), ex, acc);
        den += ex;
    }
    h2[(size_t)n * HD + lane] = elu1(acc / den + b2[lane]);
}

// ---------------- K8: per-graph mean pool of h2 ----------------
__global__ __launch_bounds__(256) void k_pool(
    const float* __restrict__ h2, const int* __restrict__ batch,
    float* __restrict__ pooled)
{
    int g = blockIdx.x;
    int lo = 0, hi = NN;
    while (lo < hi) { int m = (lo + hi) >> 1; if (batch[m] < g) lo = m + 1; else hi = m; }
    int start = lo;
    hi = NN;
    while (lo < hi) { int m = (lo + hi) >> 1; if (batch[m] < g + 1) lo = m + 1; else hi = m; }
    int end = lo;
    int c = threadIdx.x & 63;
    int rg = threadIdx.x >> 6;
    float sum = 0.f;
    for (int n = start + rg; n < end; n += 4)
        sum += h2[(size_t)n * HD + c];
    __shared__ float red[4][64];
    red[rg][c] = sum;
    __syncthreads();
    if (threadIdx.x < 64) {
        float tot = red[0][c] + red[1][c] + red[2][c] + red[3][c];
        float cnt = (float)(end - start);
        pooled[g * HD + c] = tot / fmaxf(cnt, 1.f);
    }
}

// ---------------- K9: final linear [64,64]@[64,10]+bl ----------------
__global__ __launch_bounds__(256) void k_final(
    const float* __restrict__ pooled, const float* __restrict__ Wl,
    const float* __restrict__ bl, float* __restrict__ out)
{
    int t = blockIdx.x * 256 + threadIdx.x;
    if (t >= NG * OUTC) return;
    int g = t / OUTC, o = t % OUTC;
    float acc = bl[o];
    #pragma unroll
    for (int k = 0; k < HD; k++)
        acc = fmaf(pooled[g * HD + k], Wl[k * OUTC + o], acc);
    out[t] = acc;
}

extern "C" void kernel_launch(void* const* d_in, const int* in_sizes, int n_in,
                              void* d_out, int out_size, void* d_ws, size_t ws_size,
                              hipStream_t stream) {
    const float* x     = (const float*)d_in[0];
    const int*   ei    = (const int*)d_in[1];
    const int*   batch = (const int*)d_in[2];
    const float* W1    = (const float*)d_in[3];
    const float* as1   = (const float*)d_in[4];
    const float* ad1   = (const float*)d_in[5];
    const float* b1    = (const float*)d_in[6];
    const float* W2    = (const float*)d_in[7];
    const float* as2   = (const float*)d_in[8];
    const float* ad2   = (const float*)d_in[9];
    const float* b2    = (const float*)d_in[10];
    const float* Wl    = (const float*)d_in[11];
    const float* bl    = (const float*)d_in[12];
    float* out = (float*)d_out;

    char* w = (char*)d_ws;
    size_t off = 0;
    auto alloc = [&](size_t bytes) {
        void* p = (void*)(w + off);
        off = (off + bytes + 255) & ~(size_t)255;
        return p;
    };
    // zero-initialized block first (deg + cursor)
    int* deg    = (int*)alloc((size_t)NN * 4);
    int* cursor = (int*)alloc((size_t)NN * 4);
    size_t zbytes = off;
    int* part   = (int*)alloc((size_t)NBS * 4);
    int* rowptr = (int*)alloc((size_t)(NN + 1) * 4);
    int* eidx   = (int*)alloc((size_t)NET * 4);
    unsigned short* xp1 = (unsigned short*)alloc((size_t)NN * FH1 * 2);
    unsigned short* h1  = (unsigned short*)alloc((size_t)NN * FH1 * 2);
    float* s1t = (float*)alloc((size_t)NN * 4 * 4);
    float* d1s = (float*)alloc((size_t)NN * 4 * 4);
    unsigned short* xp2 = (unsigned short*)alloc((size_t)NN * HD * 2);
    float* s2  = (float*)alloc((size_t)NN * 4);
    float* d2s = (float*)alloc((size_t)NN * 4);
    float* h2  = (float*)alloc((size_t)NN * HD * 4);
    float* pooled = (float*)alloc((size_t)NG * HD * 4);

    hipMemsetAsync(d_ws, 0, zbytes, stream);

    // CSR build
    k_hist   <<<(NET + 255) / 256, 256, 0, stream>>>(ei, deg);
    k_scan_a <<<NBS, 256, 0, stream>>>(deg, part);
    k_scan_b <<<1, 256, 0, stream>>>(part, rowptr);
    k_scan_c <<<NBS, 256, 0, stream>>>(deg, part, rowptr);
    k_scatter<<<(NET + 255) / 256, 256, 0, stream>>>(ei, rowptr, cursor, eidx);

    dim3 g1((NN + 63) / 64, 4);
    k_gemm1<<<g1, 256, 0, stream>>>(x, W1, as1, ad1, xp1, s1t, d1s);
    k_pull1<<<(NN + 3) / 4, 256, 0, stream>>>(rowptr, eidx, s1t, d1s, xp1, b1, h1);
    k_gemm2<<<(NN + 63) / 64, 256, 0, stream>>>(h1, W2, as2, ad2, xp2, s2, d2s);
    k_pull2<<<(NN + 3) / 4, 256, 0, stream>>>(rowptr, eidx, s2, d2s, xp2, b2, h2);
    k_pool <<<NG, 256, 0, stream>>>(h2, batch, pooled);
    k_final<<<(NG * OUTC + 255) / 256, 256, 0, stream>>>(pooled, Wl, bl, out);
}

// Round 7
// 287.685 us; speedup vs baseline: 13.9685x; 1.1790x over previous
//
#include <hip/hip_runtime.h>
#include <hip/hip_bf16.h>
#include <cstdint>

#define NN   50000      // nodes
#define NE   800000     // edges (without self loops)
#define NET  850000     // edges + self loops
#define FIN  128
#define FH1  256        // heads*C layer1
#define HD   64
#define NG   64
#define OUTC 10
#define NBS  ((NN + 255) / 256)   // 196 scan blocks

typedef __attribute__((ext_vector_type(8))) short short8v;
typedef __attribute__((ext_vector_type(4))) float f32x4;

__device__ __forceinline__ float bf2f(unsigned short u) {
    union { unsigned int i; float f; } v; v.i = ((unsigned int)u) << 16; return v.f;
}
__device__ __forceinline__ float bflo(unsigned int u) {
    union { unsigned int i; float f; } v; v.i = u << 16; return v.f;
}
__device__ __forceinline__ float bfhi(unsigned int u) {
    union { unsigned int i; float f; } v; v.i = u & 0xFFFF0000u; return v.f;
}
__device__ __forceinline__ unsigned short f2bf(float f) {
    union { float fl; unsigned int i; } v; v.fl = f;
    unsigned int x = v.i;
    return (unsigned short)((x + 0x7FFFu + ((x >> 16) & 1u)) >> 16);
}
__device__ __forceinline__ float leakyr(float v) { return v > 0.f ? v : 0.2f * v; }
__device__ __forceinline__ float elu1(float v)  { return v > 0.f ? v : expm1f(v); }

// ---------------- K1: xp1 = x @ W1 (bf16 out, MFMA) + scores s1t, d1 ----------------
// grid (ceil(NN/64), 4 heads); block 256 = 4 waves; 64x64 tile, BK=32.
// Wave w computes output rows [16w,16w+16); 4 col-tiles of 16.
__global__ __launch_bounds__(256) void k_gemm1(
    const float* __restrict__ x, const float* __restrict__ W1,
    const float* __restrict__ asrc, const float* __restrict__ adst,
    unsigned short* __restrict__ xp1, float* __restrict__ s1t, float* __restrict__ d1)
{
    // padded rows: 40 shorts = 80 B (20 banks) -> <=2-way conflicts
    __shared__ __align__(16) short Ash[64 * 40];
    __shared__ __align__(16) short Bsh[64 * 40];
    int row0 = blockIdx.x * 64;
    int head = blockIdx.y;
    int n0   = head * 64;
    int tid  = threadIdx.x;
    int wv   = tid >> 6;
    int lane = tid & 63;
    int g    = lane >> 4;          // k-group 0..3
    int c    = lane & 15;          // col-in-tile / row-in-tile index

    f32x4 acc[4] = {{0,0,0,0},{0,0,0,0},{0,0,0,0},{0,0,0,0}};

    int sr = tid >> 2;             // staging row 0..63
    int sq = tid & 3;              // staging k-quad 0..3

    for (int k0 = 0; k0 < FIN; k0 += 32) {
        // stage A: x[row0..+64][k0..+32] -> bf16
        {
            int gr = row0 + sr;
            float4 v0 = make_float4(0,0,0,0), v1 = make_float4(0,0,0,0);
            if (gr < NN) {
                const float4* p = reinterpret_cast<const float4*>(x + (size_t)gr * FIN + k0 + sq * 8);
                v0 = p[0]; v1 = p[1];
            }
            short8v pk;
            pk[0] = (short)f2bf(v0.x); pk[1] = (short)f2bf(v0.y);
            pk[2] = (short)f2bf(v0.z); pk[3] = (short)f2bf(v0.w);
            pk[4] = (short)f2bf(v1.x); pk[5] = (short)f2bf(v1.y);
            pk[6] = (short)f2bf(v1.z); pk[7] = (short)f2bf(v1.w);
            *reinterpret_cast<short8v*>(&Ash[sr * 40 + sq * 8]) = pk;
        }
        // stage B transposed: W1[k0..+32][n0..+64] -> Bsh[n][k]
        {
            int n  = tid & 63;
            int kg = tid >> 6;
            short8v pk;
            #pragma unroll
            for (int i = 0; i < 8; i++)
                pk[i] = (short)f2bf(W1[(size_t)(k0 + kg * 8 + i) * FH1 + n0 + n]);
            *reinterpret_cast<short8v*>(&Bsh[n * 40 + kg * 8]) = pk;
        }
        __syncthreads();
        short8v af = *reinterpret_cast<const short8v*>(&Ash[(16 * wv + c) * 40 + g * 8]);
        #pragma unroll
        for (int j = 0; j < 4; j++) {
            short8v bf = *reinterpret_cast<const short8v*>(&Bsh[(16 * j + c) * 40 + g * 8]);
            acc[j] = __builtin_amdgcn_mfma_f32_16x16x32_bf16(af, bf, acc[j], 0, 0, 0);
        }
        __syncthreads();
    }

    // epilogue: C/D layout col = lane&15 (+16j), row = 4*(lane>>4)+reg (+16*wv)
    float as[4], ad[4];
    #pragma unroll
    for (int j = 0; j < 4; j++) {
        as[j] = asrc[n0 + 16 * j + c];
        ad[j] = adst[n0 + 16 * j + c];
    }
    #pragma unroll
    for (int r = 0; r < 4; r++) {
        int row = row0 + 16 * wv + 4 * g + r;
        float sv = 0.f, dv = 0.f;
        #pragma unroll
        for (int j = 0; j < 4; j++) {
            float v = acc[j][r];
            sv = fmaf(v, as[j], sv);
            dv = fmaf(v, ad[j], dv);
            if (row < NN) xp1[(size_t)row * FH1 + n0 + 16 * j + c] = f2bf(v);
        }
        #pragma unroll
        for (int off = 8; off >= 1; off >>= 1) {
            sv += __shfl_xor(sv, off, 16);
            dv += __shfl_xor(dv, off, 16);
        }
        if (c == 0 && row < NN) {
            s1t[(size_t)head * NN + row] = sv;
            d1[row * 4 + head] = dv;
        }
    }
}

// ---------------- CSR build: histogram of dst ----------------
__global__ __launch_bounds__(256) void k_hist(
    const int* __restrict__ ei, int* __restrict__ deg)
{
    int e = blockIdx.x * 256 + threadIdx.x;
    if (e >= NET) return;
    int dst = (e < NE) ? ei[NE + e] : (e - NE);
    atomicAdd(&deg[dst], 1);
}

// ---------------- hierarchical scan: phase A (block sums) ----------------
__global__ __launch_bounds__(256) void k_scan_a(
    const int* __restrict__ deg, int* __restrict__ part)
{
    __shared__ int sm[256];
    int t = threadIdx.x;
    int idx = blockIdx.x * 256 + t;
    sm[t] = (idx < NN) ? deg[idx] : 0;
    __syncthreads();
    for (int off = 128; off >= 1; off >>= 1) {
        if (t < off) sm[t] += sm[t + off];
        __syncthreads();
    }
    if (t == 0) part[blockIdx.x] = sm[0];
}

// ---------------- phase B: scan the 196 partials (1 block) ----------------
__global__ __launch_bounds__(256) void k_scan_b(
    int* __restrict__ part, int* __restrict__ rowptr)
{
    __shared__ int sm[256];
    int t = threadIdx.x;
    int v = (t < NBS) ? part[t] : 0;
    sm[t] = v;
    __syncthreads();
    for (int off = 1; off < 256; off <<= 1) {
        int u = (t >= off) ? sm[t - off] : 0;
        __syncthreads();
        sm[t] += u;
        __syncthreads();
    }
    if (t < NBS) part[t] = sm[t] - v;   // exclusive prefix of block sums
    if (t == 0) rowptr[NN] = NET;
}

// ---------------- phase C: per-block rescan + offset -> rowptr ----------------
__global__ __launch_bounds__(256) void k_scan_c(
    const int* __restrict__ deg, const int* __restrict__ part,
    int* __restrict__ rowptr)
{
    __shared__ int sm[256];
    int t = threadIdx.x;
    int idx = blockIdx.x * 256 + t;
    int v = (idx < NN) ? deg[idx] : 0;
    sm[t] = v;
    __syncthreads();
    for (int off = 1; off < 256; off <<= 1) {
        int u = (t >= off) ? sm[t - off] : 0;
        __syncthreads();
        sm[t] += u;
        __syncthreads();
    }
    if (idx < NN) rowptr[idx] = part[blockIdx.x] + sm[t] - v;
}

// ---------------- CSR build: scatter edge srcs into slots ----------------
__global__ __launch_bounds__(256) void k_scatter(
    const int* __restrict__ ei, const int* __restrict__ rowptr,
    int* __restrict__ cursor, int* __restrict__ eidx)
{
    int e = blockIdx.x * 256 + threadIdx.x;
    if (e >= NET) return;
    int src, dst;
    if (e < NE) { src = ei[e]; dst = ei[NE + e]; }
    else        { src = dst = e - NE; }
    int pos = atomicAdd(&cursor[dst], 1);
    eidx[rowptr[dst] + pos] = src;
}

// ---------------- K3': layer-1 pull — scalar-pipe addressing, 8-way MLP ----------------
__global__ __launch_bounds__(256) void k_pull1(
    const int* __restrict__ rowptr, const int* __restrict__ eidx,
    const float* __restrict__ s1t, const float* __restrict__ d1,
    const unsigned short* __restrict__ xp1, const float* __restrict__ b1,
    unsigned short* __restrict__ h1)
{
    int wv = threadIdx.x >> 6;
    int lane = threadIdx.x & 63;
    int n = blockIdx.x * 4 + wv;
    if (n >= NN) return;
    int head = lane >> 4;                  // 16 lanes per head
    int c0 = lane * 4;                     // 4 consecutive cols per lane
    int hNN = head * NN;                   // per-lane, loop-invariant score offset
    float dv = d1[(size_t)n * 4 + head];
    int jb = __builtin_amdgcn_readfirstlane(rowptr[n]);
    int je = __builtin_amdgcn_readfirstlane(rowptr[n + 1]);
    float a0 = 0.f, a1 = 0.f, a2 = 0.f, a3 = 0.f;
    float den = 0.f;
    int j = jb;
    for (; j + 8 <= je; j += 8) {
        int s[8];
        #pragma unroll
        for (int q = 0; q < 8; q++) s[q] = eidx[j + q];       // uniform -> s_load
        float sc[8];
        uint2 u[8];
        #pragma unroll
        for (int q = 0; q < 8; q++) {
            const float* srow = s1t + s[q];
            sc[q] = srow[hNN];
            const unsigned short* xrow = xp1 + (size_t)s[q] * FH1;
            u[q] = *reinterpret_cast<const uint2*>(xrow + c0);
        }
        #pragma unroll
        for (int q = 0; q < 8; q++) {
            float ex = __expf(leakyr(sc[q] + dv));
            a0 = fmaf(bflo(u[q].x), ex, a0);
            a1 = fmaf(bfhi(u[q].x), ex, a1);
            a2 = fmaf(bflo(u[q].y), ex, a2);
            a3 = fmaf(bfhi(u[q].y), ex, a3);
            den += ex;
        }
    }
    for (; j < je; j++) {
        int src = eidx[j];
        const float* srow = s1t + src;
        float ex = __expf(leakyr(srow[hNN] + dv));
        const unsigned short* xrow = xp1 + (size_t)src * FH1;
        uint2 u = *reinterpret_cast<const uint2*>(xrow + c0);
        a0 = fmaf(bflo(u.x), ex, a0);
        a1 = fmaf(bfhi(u.x), ex, a1);
        a2 = fmaf(bflo(u.y), ex, a2);
        a3 = fmaf(bfhi(u.y), ex, a3);
        den += ex;
    }
    float inv = 1.0f / den;
    float4 b = *reinterpret_cast<const float4*>(b1 + c0);
    ushort4 st;
    st.x = f2bf(elu1(fmaf(a0, inv, b.x)));
    st.y = f2bf(elu1(fmaf(a1, inv, b.y)));
    st.z = f2bf(elu1(fmaf(a2, inv, b.z)));
    st.w = f2bf(elu1(fmaf(a3, inv, b.w)));
    *reinterpret_cast<ushort4*>(h1 + (size_t)n * FH1 + c0) = st;
}

// ---------------- K5: xp2 = h1 @ W2 (bf16 out, MFMA) + scores s2,d2 ----------------
// grid ceil(NN/64); block 256 = 4 waves; 64x64 tile, BK=32, K=256.
__global__ __launch_bounds__(256) void k_gemm2(
    const unsigned short* __restrict__ h1, const float* __restrict__ W2,
    const float* __restrict__ asrc2, const float* __restrict__ adst2,
    unsigned short* __restrict__ xp2, float* __restrict__ s2, float* __restrict__ d2)
{
    __shared__ __align__(16) short Ash[64 * 40];
    __shared__ __align__(16) short Bsh[64 * 40];
    int row0 = blockIdx.x * 64;
    int tid  = threadIdx.x;
    int wv   = tid >> 6;
    int lane = tid & 63;
    int g    = lane >> 4;
    int c    = lane & 15;

    f32x4 acc[4] = {{0,0,0,0},{0,0,0,0},{0,0,0,0},{0,0,0,0}};

    int sr = tid >> 2;
    int sq = tid & 3;

    for (int k0 = 0; k0 < FH1; k0 += 32) {
        // stage A: h1 rows (already bf16)
        {
            int gr = row0 + sr;
            uint4 v = make_uint4(0, 0, 0, 0);
            if (gr < NN) v = *reinterpret_cast<const uint4*>(h1 + (size_t)gr * FH1 + k0 + sq * 8);
            *reinterpret_cast<uint4*>(&Ash[sr * 40 + sq * 8]) = v;
        }
        // stage B transposed: W2[k0..+32][0..64)
        {
            int n  = tid & 63;
            int kg = tid >> 6;
            short8v pk;
            #pragma unroll
            for (int i = 0; i < 8; i++)
                pk[i] = (short)f2bf(W2[(size_t)(k0 + kg * 8 + i) * HD + n]);
            *reinterpret_cast<short8v*>(&Bsh[n * 40 + kg * 8]) = pk;
        }
        __syncthreads();
        short8v af = *reinterpret_cast<const short8v*>(&Ash[(16 * wv + c) * 40 + g * 8]);
        #pragma unroll
        for (int j = 0; j < 4; j++) {
            short8v bf = *reinterpret_cast<const short8v*>(&Bsh[(16 * j + c) * 40 + g * 8]);
            acc[j] = __builtin_amdgcn_mfma_f32_16x16x32_bf16(af, bf, acc[j], 0, 0, 0);
        }
        __syncthreads();
    }

    float as[4], ad[4];
    #pragma unroll
    for (int j = 0; j < 4; j++) {
        as[j] = asrc2[16 * j + c];
        ad[j] = adst2[16 * j + c];
    }
    #pragma unroll
    for (int r = 0; r < 4; r++) {
        int row = row0 + 16 * wv + 4 * g + r;
        float sv = 0.f, dv = 0.f;
        #pragma unroll
        for (int j = 0; j < 4; j++) {
            float v = acc[j][r];
            sv = fmaf(v, as[j], sv);
            dv = fmaf(v, ad[j], dv);
            if (row < NN) xp2[(size_t)row * HD + 16 * j + c] = f2bf(v);
        }
        #pragma unroll
        for (int off = 8; off >= 1; off >>= 1) {
            sv += __shfl_xor(sv, off, 16);
            dv += __shfl_xor(dv, off, 16);
        }
        if (c == 0 && row < NN) { s2[row] = sv; d2[row] = dv; }
    }
}

// ---------------- K7': layer-2 pull — 2 edges per wave (half-wave each) ----------------
__global__ __launch_bounds__(256) void k_pull2(
    const int* __restrict__ rowptr, const int* __restrict__ eidx,
    const float* __restrict__ s2, const float* __restrict__ d2,
    const unsigned short* __restrict__ xp2, const float* __restrict__ b2,
    float* __restrict__ h2)
{
    int wv = threadIdx.x >> 6;
    int lane = threadIdx.x & 63;
    int n = blockIdx.x * 4 + wv;
    if (n >= NN) return;
    int half = lane >> 5;          // which edge of the pair
    int c = lane & 31;             // 2 cols per lane: 2c, 2c+1
    float dv = d2[n];
    int jb = __builtin_amdgcn_readfirstlane(rowptr[n]);
    int je = __builtin_amdgcn_readfirstlane(rowptr[n + 1]);
    float a0 = 0.f, a1 = 0.f, den = 0.f;
    int j = jb;
    for (; j + 16 <= je; j += 16) {
        #pragma unroll
        for (int p = 0; p < 8; p++) {
            int e = j + 2 * p + half;
            int src = eidx[e];
            float sc = s2[src];
            unsigned int u = *reinterpret_cast<const unsigned int*>(xp2 + (size_t)src * HD + 2 * c);
            float ex = __expf(leakyr(sc + dv));
            a0 = fmaf(bflo(u), ex, a0);
            a1 = fmaf(bfhi(u), ex, a1);
            den += ex;
        }
    }
    for (; j < je; j += 2) {
        int e = j + half;
        bool valid = e < je;
        int ec = valid ? e : (je - 1);
        int src = eidx[ec];
        float sc = s2[src];
        unsigned int u = *reinterpret_cast<const unsigned int*>(xp2 + (size_t)src * HD + 2 * c);
        float ex = valid ? __expf(leakyr(sc + dv)) : 0.f;
        a0 = fmaf(bflo(u), ex, a0);
        a1 = fmaf(bfhi(u), ex, a1);
        den += ex;
    }
    a0 += __shfl_xor(a0, 32);
    a1 += __shfl_xor(a1, 32);
    den += __shfl_xor(den, 32);
    if (half == 0) {
        float inv = 1.0f / den;
        float2 bb = *reinterpret_cast<const float2*>(b2 + 2 * c);
        float2 o;
        o.x = elu1(fmaf(a0, inv, bb.x));
        o.y = elu1(fmaf(a1, inv, bb.y));
        *reinterpret_cast<float2*>(h2 + (size_t)n * HD + 2 * c) = o;
    }
}

// ---------------- K8: per-graph mean pool of h2 ----------------
__global__ __launch_bounds__(256) void k_pool(
    const float* __restrict__ h2, const int* __restrict__ batch,
    float* __restrict__ pooled)
{
    int g = blockIdx.x;
    int lo = 0, hi = NN;
    while (lo < hi) { int m = (lo + hi) >> 1; if (batch[m] < g) lo = m + 1; else hi = m; }
    int start = lo;
    hi = NN;
    while (lo < hi) { int m = (lo + hi) >> 1; if (batch[m] < g + 1) lo = m + 1; else hi = m; }
    int end = lo;
    int c = threadIdx.x & 63;
    int rg = threadIdx.x >> 6;
    float sum = 0.f;
    for (int n = start + rg; n < end; n += 4)
        sum += h2[(size_t)n * HD + c];
    __shared__ float red[4][64];
    red[rg][c] = sum;
    __syncthreads();
    if (threadIdx.x < 64) {
        float tot = red[0][c] + red[1][c] + red[2][c] + red[3][c];
        float cnt = (float)(end - start);
        pooled[g * HD + c] = tot / fmaxf(cnt, 1.f);
    }
}

// ---------------- K9: final linear [64,64]@[64,10]+bl ----------------
__global__ __launch_bounds__(256) void k_final(
    const float* __restrict__ pooled, const float* __restrict__ Wl,
    const float* __restrict__ bl, float* __restrict__ out)
{
    int t = blockIdx.x * 256 + threadIdx.x;
    if (t >= NG * OUTC) return;
    int g = t / OUTC, o = t % OUTC;
    float acc = bl[o];
    #pragma unroll
    for (int k = 0; k < HD; k++)
        acc = fmaf(pooled[g * HD + k], Wl[k * OUTC + o], acc);
    out[t] = acc;
}

extern "C" void kernel_launch(void* const* d_in, const int* in_sizes, int n_in,
                              void* d_out, int out_size, void* d_ws, size_t ws_size,
                              hipStream_t stream) {
    const float* x     = (const float*)d_in[0];
    const int*   ei    = (const int*)d_in[1];
    const int*   batch = (const int*)d_in[2];
    const float* W1    = (const float*)d_in[3];
    const float* as1   = (const float*)d_in[4];
    const float* ad1   = (const float*)d_in[5];
    const float* b1    = (const float*)d_in[6];
    const float* W2    = (const float*)d_in[7];
    const float* as2   = (const float*)d_in[8];
    const float* ad2   = (const float*)d_in[9];
    const float* b2    = (const float*)d_in[10];
    const float* Wl    = (const float*)d_in[11];
    const float* bl    = (const float*)d_in[12];
    float* out = (float*)d_out;

    char* w = (char*)d_ws;
    size_t off = 0;
    auto alloc = [&](size_t bytes) {
        void* p = (void*)(w + off);
        off = (off + bytes + 255) & ~(size_t)255;
        return p;
    };
    // zero-initialized block first (deg + cursor)
    int* deg    = (int*)alloc((size_t)NN * 4);
    int* cursor = (int*)alloc((size_t)NN * 4);
    size_t zbytes = off;
    int* part   = (int*)alloc((size_t)NBS * 4);
    int* rowptr = (int*)alloc((size_t)(NN + 1) * 4);
    int* eidx   = (int*)alloc((size_t)NET * 4);
    unsigned short* xp1 = (unsigned short*)alloc((size_t)NN * FH1 * 2);
    unsigned short* h1  = (unsigned short*)alloc((size_t)NN * FH1 * 2);
    float* s1t = (float*)alloc((size_t)NN * 4 * 4);
    float* d1s = (float*)alloc((size_t)NN * 4 * 4);
    unsigned short* xp2 = (unsigned short*)alloc((size_t)NN * HD * 2);
    float* s2  = (float*)alloc((size_t)NN * 4);
    float* d2s = (float*)alloc((size_t)NN * 4);
    float* h2  = (float*)alloc((size_t)NN * HD * 4);
    float* pooled = (float*)alloc((size_t)NG * HD * 4);

    hipMemsetAsync(d_ws, 0, zbytes, stream);

    // CSR build
    k_hist   <<<(NET + 255) / 256, 256, 0, stream>>>(ei, deg);
    k_scan_a <<<NBS, 256, 0, stream>>>(deg, part);
    k_scan_b <<<1, 256, 0, stream>>>(part, rowptr);
    k_scan_c <<<NBS, 256, 0, stream>>>(deg, part, rowptr);
    k_scatter<<<(NET + 255) / 256, 256, 0, stream>>>(ei, rowptr, cursor, eidx);

    dim3 g1((NN + 63) / 64, 4);
    k_gemm1<<<g1, 256, 0, stream>>>(x, W1, as1, ad1, xp1, s1t, d1s);
    k_pull1<<<(NN + 3) / 4, 256, 0, stream>>>(rowptr, eidx, s1t, d1s, xp1, b1, h1);
    k_gemm2<<<(NN + 63) / 64, 256, 0, stream>>>(h1, W2, as2, ad2, xp2, s2, d2s);
    k_pull2<<<(NN + 3) / 4, 256, 0, stream>>>(rowptr, eidx, s2, d2s, xp2, b2, h2);
    k_pool <<<NG, 256, 0, stream>>>(h2, batch, pooled);
    k_final<<<(NG * OUTC + 255) / 256, 256, 0, stream>>>(pooled, Wl, bl, out);
}

// Round 8
// 257.435 us; speedup vs baseline: 15.6099x; 1.1175x over previous
//
#include <hip/hip_runtime.h>
#include <hip/hip_bf16.h>
#include <cstdint>

#define NN   50000      // nodes
#define NE   800000     // edges (without self loops)
#define NET  850000     // edges + self loops
#define FIN  128
#define FH1  256        // heads*C layer1
#define HD   64
#define NG   64
#define OUTC 10
#define NBS  ((NN + 255) / 256)   // 196 scan blocks

typedef __attribute__((ext_vector_type(8))) short short8v;
typedef __attribute__((ext_vector_type(4))) float f32x4;

__device__ __forceinline__ float bf2f(unsigned short u) {
    union { unsigned int i; float f; } v; v.i = ((unsigned int)u) << 16; return v.f;
}
__device__ __forceinline__ float bflo(unsigned int u) {
    union { unsigned int i; float f; } v; v.i = u << 16; return v.f;
}
__device__ __forceinline__ float bfhi(unsigned int u) {
    union { unsigned int i; float f; } v; v.i = u & 0xFFFF0000u; return v.f;
}
__device__ __forceinline__ unsigned short f2bf(float f) {
    union { float fl; unsigned int i; } v; v.fl = f;
    unsigned int x = v.i;
    return (unsigned short)((x + 0x7FFFu + ((x >> 16) & 1u)) >> 16);
}
__device__ __forceinline__ float leakyr(float v) { return v > 0.f ? v : 0.2f * v; }
__device__ __forceinline__ float elu1(float v)  { return v > 0.f ? v : expm1f(v); }

// ---------------- K1: xp1 = x @ W1 (bf16 out, MFMA) + scores s1t, d1 ----------------
// grid ceil(NN/64); block 256 = 4 waves; block tile 64x256 (x staged ONCE);
// wave wv = head wv, covering cols [64wv, 64wv+64), all 64 rows (4 row-tiles).
__global__ __launch_bounds__(256) void k_gemm1(
    const float* __restrict__ x, const float* __restrict__ W1,
    const float* __restrict__ asrc, const float* __restrict__ adst,
    unsigned short* __restrict__ xp1, float* __restrict__ s1t, float* __restrict__ d1)
{
    __shared__ __align__(16) short Ash[64 * 40];    // 64 rows x 32 k (pad 40)
    __shared__ __align__(16) short Bsh[256 * 40];   // 256 n x 32 k (pad 40)
    int row0 = blockIdx.x * 64;
    int tid  = threadIdx.x;
    int wv   = tid >> 6;           // wave == head
    int lane = tid & 63;
    int g    = lane >> 4;          // k-group 0..3
    int c    = lane & 15;

    f32x4 acc[4][4];               // [row-tile][col-tile]
    #pragma unroll
    for (int i = 0; i < 4; i++)
        #pragma unroll
        for (int j = 0; j < 4; j++) acc[i][j] = (f32x4){0.f, 0.f, 0.f, 0.f};

    int sr = tid >> 2;             // staging row 0..63
    int sq = tid & 3;              // staging k-quad

    for (int k0 = 0; k0 < FIN; k0 += 32) {
        // stage A: x[row0..+64][k0..+32] -> bf16 (once per block)
        {
            int gr = row0 + sr;
            float4 v0 = make_float4(0,0,0,0), v1 = make_float4(0,0,0,0);
            if (gr < NN) {
                const float4* p = reinterpret_cast<const float4*>(x + (size_t)gr * FIN + k0 + sq * 8);
                v0 = p[0]; v1 = p[1];
            }
            short8v pk;
            pk[0] = (short)f2bf(v0.x); pk[1] = (short)f2bf(v0.y);
            pk[2] = (short)f2bf(v0.z); pk[3] = (short)f2bf(v0.w);
            pk[4] = (short)f2bf(v1.x); pk[5] = (short)f2bf(v1.y);
            pk[6] = (short)f2bf(v1.z); pk[7] = (short)f2bf(v1.w);
            *reinterpret_cast<short8v*>(&Ash[sr * 40 + sq * 8]) = pk;
        }
        // stage B transposed: W1[k0..+32][0..256) -> Bsh[n][k]; thread owns n=tid
        {
            #pragma unroll
            for (int kg = 0; kg < 4; kg++) {
                short8v pk;
                #pragma unroll
                for (int i = 0; i < 8; i++)
                    pk[i] = (short)f2bf(W1[(size_t)(k0 + kg * 8 + i) * FH1 + tid]);
                *reinterpret_cast<short8v*>(&Bsh[tid * 40 + kg * 8]) = pk;
            }
        }
        __syncthreads();
        short8v bf[4];
        #pragma unroll
        for (int j = 0; j < 4; j++)
            bf[j] = *reinterpret_cast<const short8v*>(&Bsh[(64 * wv + 16 * j + c) * 40 + g * 8]);
        #pragma unroll
        for (int rt = 0; rt < 4; rt++) {
            short8v af = *reinterpret_cast<const short8v*>(&Ash[(16 * rt + c) * 40 + g * 8]);
            #pragma unroll
            for (int j = 0; j < 4; j++)
                acc[rt][j] = __builtin_amdgcn_mfma_f32_16x16x32_bf16(af, bf[j], acc[rt][j], 0, 0, 0);
        }
        __syncthreads();
    }

    int n0 = 64 * wv;
    float as[4], ad[4];
    #pragma unroll
    for (int j = 0; j < 4; j++) {
        as[j] = asrc[n0 + 16 * j + c];
        ad[j] = adst[n0 + 16 * j + c];
    }
    #pragma unroll
    for (int rt = 0; rt < 4; rt++) {
        #pragma unroll
        for (int r = 0; r < 4; r++) {
            int row = row0 + 16 * rt + 4 * g + r;
            float sv = 0.f, dv = 0.f;
            #pragma unroll
            for (int j = 0; j < 4; j++) {
                float v = acc[rt][j][r];
                sv = fmaf(v, as[j], sv);
                dv = fmaf(v, ad[j], dv);
                if (row < NN) xp1[(size_t)row * FH1 + n0 + 16 * j + c] = f2bf(v);
            }
            #pragma unroll
            for (int off = 8; off >= 1; off >>= 1) {
                sv += __shfl_xor(sv, off, 16);
                dv += __shfl_xor(dv, off, 16);
            }
            if (c == 0 && row < NN) {
                s1t[(size_t)wv * NN + row] = sv;
                d1[row * 4 + wv] = dv;
            }
        }
    }
}

// ---------------- CSR build: histogram of dst ----------------
__global__ __launch_bounds__(256) void k_hist(
    const int* __restrict__ ei, int* __restrict__ deg)
{
    int e = blockIdx.x * 256 + threadIdx.x;
    if (e >= NET) return;
    int dst = (e < NE) ? ei[NE + e] : (e - NE);
    atomicAdd(&deg[dst], 1);
}

// ---------------- hierarchical scan: phase A (block sums) ----------------
__global__ __launch_bounds__(256) void k_scan_a(
    const int* __restrict__ deg, int* __restrict__ part)
{
    __shared__ int sm[256];
    int t = threadIdx.x;
    int idx = blockIdx.x * 256 + t;
    sm[t] = (idx < NN) ? deg[idx] : 0;
    __syncthreads();
    for (int off = 128; off >= 1; off >>= 1) {
        if (t < off) sm[t] += sm[t + off];
        __syncthreads();
    }
    if (t == 0) part[blockIdx.x] = sm[0];
}

// ---------------- phase B: scan the 196 partials (1 block) ----------------
__global__ __launch_bounds__(256) void k_scan_b(
    int* __restrict__ part, int* __restrict__ rowptr)
{
    __shared__ int sm[256];
    int t = threadIdx.x;
    int v = (t < NBS) ? part[t] : 0;
    sm[t] = v;
    __syncthreads();
    for (int off = 1; off < 256; off <<= 1) {
        int u = (t >= off) ? sm[t - off] : 0;
        __syncthreads();
        sm[t] += u;
        __syncthreads();
    }
    if (t < NBS) part[t] = sm[t] - v;   // exclusive prefix of block sums
    if (t == 0) rowptr[NN] = NET;
}

// ---------------- phase C: per-block rescan + offset -> rowptr ----------------
__global__ __launch_bounds__(256) void k_scan_c(
    const int* __restrict__ deg, const int* __restrict__ part,
    int* __restrict__ rowptr)
{
    __shared__ int sm[256];
    int t = threadIdx.x;
    int idx = blockIdx.x * 256 + t;
    int v = (idx < NN) ? deg[idx] : 0;
    sm[t] = v;
    __syncthreads();
    for (int off = 1; off < 256; off <<= 1) {
        int u = (t >= off) ? sm[t - off] : 0;
        __syncthreads();
        sm[t] += u;
        __syncthreads();
    }
    if (idx < NN) rowptr[idx] = part[blockIdx.x] + sm[t] - v;
}

// ---------------- CSR build: scatter edge srcs into slots ----------------
__global__ __launch_bounds__(256) void k_scatter(
    const int* __restrict__ ei, const int* __restrict__ rowptr,
    int* __restrict__ cursor, int* __restrict__ eidx)
{
    int e = blockIdx.x * 256 + threadIdx.x;
    if (e >= NET) return;
    int src, dst;
    if (e < NE) { src = ei[e]; dst = ei[NE + e]; }
    else        { src = dst = e - NE; }
    int pos = atomicAdd(&cursor[dst], 1);
    eidx[rowptr[dst] + pos] = src;
}

// ---------------- K3': layer-1 pull — scalar-pipe addressing, 8-way MLP ----------------
__global__ __launch_bounds__(256) void k_pull1(
    const int* __restrict__ rowptr, const int* __restrict__ eidx,
    const float* __restrict__ s1t, const float* __restrict__ d1,
    const unsigned short* __restrict__ xp1, const float* __restrict__ b1,
    unsigned short* __restrict__ h1)
{
    int wv = threadIdx.x >> 6;
    int lane = threadIdx.x & 63;
    int n = blockIdx.x * 4 + wv;
    if (n >= NN) return;
    int head = lane >> 4;                  // 16 lanes per head
    int c0 = lane * 4;                     // 4 consecutive cols per lane
    int hNN = head * NN;                   // per-lane, loop-invariant score offset
    float dv = d1[(size_t)n * 4 + head];
    int jb = __builtin_amdgcn_readfirstlane(rowptr[n]);
    int je = __builtin_amdgcn_readfirstlane(rowptr[n + 1]);
    float a0 = 0.f, a1 = 0.f, a2 = 0.f, a3 = 0.f;
    float den = 0.f;
    int j = jb;
    for (; j + 8 <= je; j += 8) {
        int s[8];
        #pragma unroll
        for (int q = 0; q < 8; q++) s[q] = eidx[j + q];       // uniform -> s_load
        float sc[8];
        uint2 u[8];
        #pragma unroll
        for (int q = 0; q < 8; q++) {
            const float* srow = s1t + s[q];
            sc[q] = srow[hNN];
            const unsigned short* xrow = xp1 + (size_t)s[q] * FH1;
            u[q] = *reinterpret_cast<const uint2*>(xrow + c0);
        }
        #pragma unroll
        for (int q = 0; q < 8; q++) {
            float ex = __expf(leakyr(sc[q] + dv));
            a0 = fmaf(bflo(u[q].x), ex, a0);
            a1 = fmaf(bfhi(u[q].x), ex, a1);
            a2 = fmaf(bflo(u[q].y), ex, a2);
            a3 = fmaf(bfhi(u[q].y), ex, a3);
            den += ex;
        }
    }
    for (; j < je; j++) {
        int src = eidx[j];
        const float* srow = s1t + src;
        float ex = __expf(leakyr(srow[hNN] + dv));
        const unsigned short* xrow = xp1 + (size_t)src * FH1;
        uint2 u = *reinterpret_cast<const uint2*>(xrow + c0);
        a0 = fmaf(bflo(u.x), ex, a0);
        a1 = fmaf(bfhi(u.x), ex, a1);
        a2 = fmaf(bflo(u.y), ex, a2);
        a3 = fmaf(bfhi(u.y), ex, a3);
        den += ex;
    }
    float inv = 1.0f / den;
    float4 b = *reinterpret_cast<const float4*>(b1 + c0);
    ushort4 st;
    st.x = f2bf(elu1(fmaf(a0, inv, b.x)));
    st.y = f2bf(elu1(fmaf(a1, inv, b.y)));
    st.z = f2bf(elu1(fmaf(a2, inv, b.z)));
    st.w = f2bf(elu1(fmaf(a3, inv, b.w)));
    *reinterpret_cast<ushort4*>(h1 + (size_t)n * FH1 + c0) = st;
}

// ---------------- K5: xp2 = h1 @ W2 (bf16 out, MFMA) + scores s2,d2 ----------------
// grid ceil(NN/64); block 256 = 4 waves; 64x64 tile, BK=32, K=256.
__global__ __launch_bounds__(256) void k_gemm2(
    const unsigned short* __restrict__ h1, const float* __restrict__ W2,
    const float* __restrict__ asrc2, const float* __restrict__ adst2,
    unsigned short* __restrict__ xp2, float* __restrict__ s2, float* __restrict__ d2)
{
    __shared__ __align__(16) short Ash[64 * 40];
    __shared__ __align__(16) short Bsh[64 * 40];
    int row0 = blockIdx.x * 64;
    int tid  = threadIdx.x;
    int wv   = tid >> 6;
    int lane = tid & 63;
    int g    = lane >> 4;
    int c    = lane & 15;

    f32x4 acc[4] = {{0,0,0,0},{0,0,0,0},{0,0,0,0},{0,0,0,0}};

    int sr = tid >> 2;
    int sq = tid & 3;

    for (int k0 = 0; k0 < FH1; k0 += 32) {
        {
            int gr = row0 + sr;
            uint4 v = make_uint4(0, 0, 0, 0);
            if (gr < NN) v = *reinterpret_cast<const uint4*>(h1 + (size_t)gr * FH1 + k0 + sq * 8);
            *reinterpret_cast<uint4*>(&Ash[sr * 40 + sq * 8]) = v;
        }
        {
            int n  = tid & 63;
            int kg = tid >> 6;
            short8v pk;
            #pragma unroll
            for (int i = 0; i < 8; i++)
                pk[i] = (short)f2bf(W2[(size_t)(k0 + kg * 8 + i) * HD + n]);
            *reinterpret_cast<short8v*>(&Bsh[n * 40 + kg * 8]) = pk;
        }
        __syncthreads();
        short8v af = *reinterpret_cast<const short8v*>(&Ash[(16 * wv + c) * 40 + g * 8]);
        #pragma unroll
        for (int j = 0; j < 4; j++) {
            short8v bf = *reinterpret_cast<const short8v*>(&Bsh[(16 * j + c) * 40 + g * 8]);
            acc[j] = __builtin_amdgcn_mfma_f32_16x16x32_bf16(af, bf, acc[j], 0, 0, 0);
        }
        __syncthreads();
    }

    float as[4], ad[4];
    #pragma unroll
    for (int j = 0; j < 4; j++) {
        as[j] = asrc2[16 * j + c];
        ad[j] = adst2[16 * j + c];
    }
    #pragma unroll
    for (int r = 0; r < 4; r++) {
        int row = row0 + 16 * wv + 4 * g + r;
        float sv = 0.f, dv = 0.f;
        #pragma unroll
        for (int j = 0; j < 4; j++) {
            float v = acc[j][r];
            sv = fmaf(v, as[j], sv);
            dv = fmaf(v, ad[j], dv);
            if (row < NN) xp2[(size_t)row * HD + 16 * j + c] = f2bf(v);
        }
        #pragma unroll
        for (int off = 8; off >= 1; off >>= 1) {
            sv += __shfl_xor(sv, off, 16);
            dv += __shfl_xor(dv, off, 16);
        }
        if (c == 0 && row < NN) { s2[row] = sv; d2[row] = dv; }
    }
}

// ---------------- K7': layer-2 pull — 2 edges per wave (half-wave each) ----------------
__global__ __launch_bounds__(256) void k_pull2(
    const int* __restrict__ rowptr, const int* __restrict__ eidx,
    const float* __restrict__ s2, const float* __restrict__ d2,
    const unsigned short* __restrict__ xp2, const float* __restrict__ b2,
    float* __restrict__ h2)
{
    int wv = threadIdx.x >> 6;
    int lane = threadIdx.x & 63;
    int n = blockIdx.x * 4 + wv;
    if (n >= NN) return;
    int half = lane >> 5;          // which edge of the pair
    int c = lane & 31;             // 2 cols per lane: 2c, 2c+1
    float dv = d2[n];
    int jb = __builtin_amdgcn_readfirstlane(rowptr[n]);
    int je = __builtin_amdgcn_readfirstlane(rowptr[n + 1]);
    float a0 = 0.f, a1 = 0.f, den = 0.f;
    int j = jb;
    for (; j + 16 <= je; j += 16) {
        #pragma unroll
        for (int p = 0; p < 8; p++) {
            int e = j + 2 * p + half;
            int src = eidx[e];
            float sc = s2[src];
            unsigned int u = *reinterpret_cast<const unsigned int*>(xp2 + (size_t)src * HD + 2 * c);
            float ex = __expf(leakyr(sc + dv));
            a0 = fmaf(bflo(u), ex, a0);
            a1 = fmaf(bfhi(u), ex, a1);
            den += ex;
        }
    }
    for (; j < je; j += 2) {
        int e = j + half;
        bool valid = e < je;
        int ec = valid ? e : (je - 1);
        int src = eidx[ec];
        float sc = s2[src];
        unsigned int u = *reinterpret_cast<const unsigned int*>(xp2 + (size_t)src * HD + 2 * c);
        float ex = valid ? __expf(leakyr(sc + dv)) : 0.f;
        a0 = fmaf(bflo(u), ex, a0);
        a1 = fmaf(bfhi(u), ex, a1);
        den += ex;
    }
    a0 += __shfl_xor(a0, 32);
    a1 += __shfl_xor(a1, 32);
    den += __shfl_xor(den, 32);
    if (half == 0) {
        float inv = 1.0f / den;
        float2 bb = *reinterpret_cast<const float2*>(b2 + 2 * c);
        float2 o;
        o.x = elu1(fmaf(a0, inv, bb.x));
        o.y = elu1(fmaf(a1, inv, bb.y));
        *reinterpret_cast<float2*>(h2 + (size_t)n * HD + 2 * c) = o;
    }
}

// ---------------- K8: per-graph partial sums (grid NG x 8, atomic combine) ----------------
__global__ __launch_bounds__(256) void k_pool(
    const float* __restrict__ h2, const int* __restrict__ batch,
    float* __restrict__ pooled /* SUMS, pre-zeroed */)
{
    int g = blockIdx.x;
    int sslice = blockIdx.y;
    int lo = 0, hi = NN;
    while (lo < hi) { int m = (lo + hi) >> 1; if (batch[m] < g) lo = m + 1; else hi = m; }
    int start = lo;
    hi = NN;
    while (lo < hi) { int m = (lo + hi) >> 1; if (batch[m] < g + 1) lo = m + 1; else hi = m; }
    int end = lo;
    int len = end - start;
    int chunk = (len + 7) >> 3;
    int b0 = start + sslice * chunk;
    int b1 = min(b0 + chunk, end);
    int c = threadIdx.x & 63;
    int rg = threadIdx.x >> 6;
    float sum = 0.f;
    for (int n = b0 + rg; n < b1; n += 4)
        sum += h2[(size_t)n * HD + c];
    __shared__ float red[4][64];
    red[rg][c] = sum;
    __syncthreads();
    if (threadIdx.x < 64) {
        float tot = red[0][c] + red[1][c] + red[2][c] + red[3][c];
        if (tot != 0.f) atomicAdd(&pooled[g * HD + c], tot);
    }
}

// ---------------- K9: final linear (pooled are SUMS; divide by count) ----------------
__global__ __launch_bounds__(256) void k_final(
    const float* __restrict__ pooled, const int* __restrict__ batch,
    const float* __restrict__ Wl, const float* __restrict__ bl,
    float* __restrict__ out)
{
    int t = blockIdx.x * 256 + threadIdx.x;
    if (t >= NG * OUTC) return;
    int g = t / OUTC, o = t % OUTC;
    int lo = 0, hi = NN;
    while (lo < hi) { int m = (lo + hi) >> 1; if (batch[m] < g) lo = m + 1; else hi = m; }
    int start = lo;
    hi = NN;
    while (lo < hi) { int m = (lo + hi) >> 1; if (batch[m] < g + 1) lo = m + 1; else hi = m; }
    float cnt = (float)(lo - start);
    float acc = 0.f;
    #pragma unroll
    for (int k = 0; k < HD; k++)
        acc = fmaf(pooled[g * HD + k], Wl[k * OUTC + o], acc);
    out[t] = acc / fmaxf(cnt, 1.f) + bl[o];
}

extern "C" void kernel_launch(void* const* d_in, const int* in_sizes, int n_in,
                              void* d_out, int out_size, void* d_ws, size_t ws_size,
                              hipStream_t stream) {
    const float* x     = (const float*)d_in[0];
    const int*   ei    = (const int*)d_in[1];
    const int*   batch = (const int*)d_in[2];
    const float* W1    = (const float*)d_in[3];
    const float* as1   = (const float*)d_in[4];
    const float* ad1   = (const float*)d_in[5];
    const float* b1    = (const float*)d_in[6];
    const float* W2    = (const float*)d_in[7];
    const float* as2   = (const float*)d_in[8];
    const float* ad2   = (const float*)d_in[9];
    const float* b2    = (const float*)d_in[10];
    const float* Wl    = (const float*)d_in[11];
    const float* bl    = (const float*)d_in[12];
    float* out = (float*)d_out;

    char* w = (char*)d_ws;
    size_t off = 0;
    auto alloc = [&](size_t bytes) {
        void* p = (void*)(w + off);
        off = (off + bytes + 255) & ~(size_t)255;
        return p;
    };
    // zero-initialized block first (deg + cursor + pooled sums)
    int* deg    = (int*)alloc((size_t)NN * 4);
    int* cursor = (int*)alloc((size_t)NN * 4);
    float* pooled = (float*)alloc((size_t)NG * HD * 4);
    size_t zbytes = off;
    int* part   = (int*)alloc((size_t)NBS * 4);
    int* rowptr = (int*)alloc((size_t)(NN + 1) * 4);
    int* eidx   = (int*)alloc((size_t)NET * 4);
    unsigned short* xp1 = (unsigned short*)alloc((size_t)NN * FH1 * 2);
    unsigned short* h1  = (unsigned short*)alloc((size_t)NN * FH1 * 2);
    float* s1t = (float*)alloc((size_t)NN * 4 * 4);
    float* d1s = (float*)alloc((size_t)NN * 4 * 4);
    unsigned short* xp2 = (unsigned short*)alloc((size_t)NN * HD * 2);
    float* s2  = (float*)alloc((size_t)NN * 4);
    float* d2s = (float*)alloc((size_t)NN * 4);
    float* h2  = (float*)alloc((size_t)NN * HD * 4);

    hipMemsetAsync(d_ws, 0, zbytes, stream);

    // CSR build
    k_hist   <<<(NET + 255) / 256, 256, 0, stream>>>(ei, deg);
    k_scan_a <<<NBS, 256, 0, stream>>>(deg, part);
    k_scan_b <<<1, 256, 0, stream>>>(part, rowptr);
    k_scan_c <<<NBS, 256, 0, stream>>>(deg, part, rowptr);
    k_scatter<<<(NET + 255) / 256, 256, 0, stream>>>(ei, rowptr, cursor, eidx);

    k_gemm1<<<(NN + 63) / 64, 256, 0, stream>>>(x, W1, as1, ad1, xp1, s1t, d1s);
    k_pull1<<<(NN + 3) / 4, 256, 0, stream>>>(rowptr, eidx, s1t, d1s, xp1, b1, h1);
    k_gemm2<<<(NN + 63) / 64, 256, 0, stream>>>(h1, W2, as2, ad2, xp2, s2, d2s);
    k_pull2<<<(NN + 3) / 4, 256, 0, stream>>>(rowptr, eidx, s2, d2s, xp2, b2, h2);
    dim3 gp(NG, 8);
    k_pool <<<gp, 256, 0, stream>>>(h2, batch, pooled);
    k_final<<<(NG * OUTC + 255) / 256, 256, 0, stream>>>(pooled, batch, Wl, bl, out);
}